// Round 11
// baseline (657.441 us; speedup 1.0000x reference)
//
#include <hip/hip_runtime.h>
#include <hip/hip_bf16.h>
#include <cstdint>

// ---------------------------------------------------------------------------
// DGCNN forward on MI355X. Math f32; conv1d via bf16 MFMA on packed
// fragment layouts; kNN via symmetric dist GEMM + register-queue wave top-k.
// R11: edge_pass v2 (float4 o-quad gather, 1/4 VMEM instructions);
// dist2 symmetric-triangle (36/64 tiles + mirror write).
// ---------------------------------------------------------------------------

static constexpr int BB  = 8;
static constexpr int NN  = 1024;
static constexpr int KNB = 20;
static constexpr float BNEPS = 1e-5f;

static constexpr int NIN = 25;

__constant__ int c_cum[NIN + 1] = {
    0, 24576, 24960, 33152, 49536, 115072, 639360,
    1687936, 1819008, 1819264, 1829504, 1829544, 1829608, 1829672, 1829736,
    1829800, 1829928, 1830056, 1830312, 1830568, 1831592, 1832616, 1833128,
    1833640, 1833896, 1834152};
__constant__ int c_trO[NIN] = {0, 64, 64, 128, 256, 1024, 0, 0, 0, 0, 0,
                               0, 0, 0, 0, 0, 0, 0, 0, 0, 0, 0, 0, 0, 0};
__constant__ int c_trI[NIN] = {0, 6, 128, 128, 256, 512, 0, 0, 0, 0, 0,
                               0, 0, 0, 0, 0, 0, 0, 0, 0, 0, 0, 0, 0, 0};
// upper-triangle 128-tile pairs (rn <= rm), 36 of them
__constant__ int c_trn[36] = {0,0,0,0,0,0,0,0, 1,1,1,1,1,1,1, 2,2,2,2,2,2,
                              3,3,3,3,3, 4,4,4,4, 5,5,5, 6,6, 7};
__constant__ int c_trm[36] = {0,1,2,3,4,5,6,7, 1,2,3,4,5,6,7, 2,3,4,5,6,7,
                              3,4,5,6,7, 4,5,6,7, 5,6,7, 6,7, 7};

enum : int {
  XIN = 0, WT1 = 24576, WT2 = 24960, WT3 = 33152, WT4 = 49536, WT5 = 115072,
  WL1 = 639360, WL2 = 1687936, BL2o = 1819008, WL3 = 1819264, BL3o = 1829504,
  G1 = 1829544, B1o = 1829608, G2 = 1829672, B2o = 1829736,
  G3 = 1829800, B3o = 1829928, G4 = 1830056, B4o = 1830312,
  G5 = 1830568, B5o = 1831592, G6 = 1832616, B6o = 1833128,
  G7 = 1833640, B7o = 1833896,
  IDXo = 1842432,       // 163840 i32
  HCATo = 2006272,      // 8*512*1024 f
  STATSo = 6200576,     // 5 layers * 4096 f
  Z2048o = 6237440,     // 8*2048 f
  Z1o = 6253824,        // 8*512 f
  Z2o = 6257920,        // 8*256 f
  FLAGSo = 6259968,     // 32 i32
  DISTo = 6260736,      // 8M-float window (sequentially reused)
  HBFo  = 14649344,     // packed bf16 h: 8*1024*512 shorts (2M float slots)
  W5BFo = 16746496      // packed bf16 w5: 512K shorts -> ends 17008640
};
static constexpr int TOTAL_IN = 1834152;
static constexpr int NCONV = (TOTAL_IN + 255) / 256;   // 7165 blocks
static constexpr int U_OFF   = DISTo + 0;
static constexpr int VD_OFF  = DISTo + 2097152;
static constexpr int YMX_OFF = DISTo + 4194304;
static constexpr int YMN_OFF = DISTo + 6291456;
static constexpr int Y5_OFF  = DISTo + 0;
static constexpr size_t WS_NEED_MFMA = (size_t)17008640 * 4;  // ~68 MB

struct Ptrs { const void* p[NIN]; };

typedef short short8v __attribute__((ext_vector_type(8)));
typedef float f32x16 __attribute__((ext_vector_type(16)));

__device__ __forceinline__ float lrelu(float y) { return (y < 0.f) ? 0.2f * y : y; }
__device__ __forceinline__ unsigned short f2b(float f) {
  unsigned u = __float_as_uint(f);
  unsigned r = (u + 0x7FFFu + ((u >> 16) & 1u)) >> 16;   // RNE
  return (unsigned short)r;
}
__device__ __forceinline__ bool kbetter(float v, int i, float v2, int i2) {
  return v > v2 || (v == v2 && i < i2);
}
__device__ __forceinline__ float load_in(const void* p, int fl, int idx) {
  if (fl == 2) return 0.f;
  if (fl == 1) {
    const unsigned short u = ((const unsigned short*)p)[idx];
    return __uint_as_float(((unsigned)u) << 16);
  }
  return ((const float*)p)[idx];
}

// ---------------------------------------------------------------------------
// dtype detection
// ---------------------------------------------------------------------------
__global__ void detect_kernel(Ptrs ptrs, int* __restrict__ flags) {
  const int i = blockIdx.x;
  const unsigned* p = (const unsigned*)ptrs.p[i];
  const int n = c_cum[i + 1] - c_cum[i];
  int words = n >> 1; if (words > 64) words = 64;
  const int t = threadIdx.x;
  unsigned w = (t < words) ? p[t] : 0u;
  bool nz = (w != 0u);
  unsigned e = (w >> 7) & 0xFFu;
  bool pl = nz && (e >= 96u) && (e <= 140u);
  unsigned long long mnz = __ballot(nz);
  unsigned long long mpl = __ballot(pl);
  if (t == 0) {
    int cnz = __popcll(mnz), cpl = __popcll(mpl);
    flags[i] = (cnz == 0) ? 2 : ((2 * cpl > words) ? 1 : 0);
  }
}

// ---------------------------------------------------------------------------
// convert: main blocks convert+transpose inputs; tail1 zeroes stats;
// tail2 packs w5 (raw input -> MFMA A-fragment bf16) if do_w5.
// ---------------------------------------------------------------------------
__global__ void convert_kernel(Ptrs ptrs, const int* __restrict__ flags,
                               float* __restrict__ ws, int do_w5) {
  const int bx = blockIdx.x;
  const int t = threadIdx.x;
  if (bx >= NCONV + 80) {            // tail2: w5 packing
    if (!do_w5) return;
    const int g = (bx - NCONV - 80) * 256 + t;   // 0..65535
    const int lane = g & 63;
    const int kb = (g >> 6) & 31;
    const int ot = g >> 11;
    const int o = ot * 32 + (lane & 31);
    const int k0 = kb * 16 + (lane >> 5) * 8;
    const void* w5raw = ptrs.p[5];
    const int fl = flags[5];
    unsigned u[4];
#pragma unroll
    for (int h = 0; h < 4; ++h) {
      const unsigned short lo = f2b(load_in(w5raw, fl, o * 512 + k0 + 2 * h));
      const unsigned short hi = f2b(load_in(w5raw, fl, o * 512 + k0 + 2 * h + 1));
      u[h] = (unsigned)lo | ((unsigned)hi << 16);
    }
    unsigned short* w5p = (unsigned short*)(ws + W5BFo);
    *(uint4*)&w5p[(size_t)g * 8] = make_uint4(u[0], u[1], u[2], u[3]);
    return;
  }
  if (bx >= NCONV) {                 // tail1: zero stats
    const int z = (bx - NCONV) * 256 + t;
    if (z < 20480) ws[STATSo + z] = 0.f;
    return;
  }
  const int e = bx * 256 + t;
  if (e >= TOTAL_IN) return;
  int i = 0;
  while (e >= c_cum[i + 1]) ++i;
  const int el = e - c_cum[i];
  int src;
  const int O = c_trO[i];
  if (O > 0) {
    const int I = c_trI[i];
    const int o = el % O, ii = el / O;
    src = o * I + ii;
  } else src = el;
  ws[e] = load_in(ptrs.p[i], flags[i], src);
}

// ---------------------------------------------------------------------------
// dist GEMM, symmetric: compute only rn<=rm 128x128 tiles (36/batch), mirror
// off-diagonal tiles. D[b][n][m] = (2*dot - xx[n]) - xx[m] — mirror entries
// recomputed with the identical expression => bitwise-symmetric D.
// ---------------------------------------------------------------------------
template <int C>
__global__ __launch_bounds__(256) void dist2_kernel(
    const float* __restrict__ xbase, int bstr, float* __restrict__ D) {
  __shared__ __align__(16) float s_a[16][128];
  __shared__ __align__(16) float s_b[16][128];
  __shared__ float s_xx[256];
  const int t = threadIdx.x;
  const int bx = blockIdx.x;
  const int b = bx / 36;
  const int r = bx % 36;
  const int tn0 = c_trn[r] * 128;
  const int tm0 = c_trm[r] * 128;
  const float* xb = xbase + (size_t)b * bstr;
  {
    const int idx = (t < 128) ? (tn0 + t) : (tm0 + (t - 128));
    float s = 0.f;
    for (int c = 0; c < C; ++c) {
      const float v = xb[c * NN + idx];
      s = fmaf(v, v, s);
    }
    s_xx[t] = s;
  }
  const int tn = (t >> 4) * 8;
  const int tm = (t & 15) * 8;
  float acc[8][8] = {};
  for (int c0 = 0; c0 < C; c0 += 16) {
    const int kc = (C - c0 < 16) ? (C - c0) : 16;
    __syncthreads();
    for (int i = t; i < 512; i += 256) {
      const int cc = i >> 5, col4 = (i & 31) * 4;
      float4 va = make_float4(0.f, 0.f, 0.f, 0.f), vb = va;
      if (cc < kc) {
        va = *(const float4*)&xb[(c0 + cc) * NN + tn0 + col4];
        vb = *(const float4*)&xb[(c0 + cc) * NN + tm0 + col4];
      }
      *(float4*)&s_a[cc][col4] = va;
      *(float4*)&s_b[cc][col4] = vb;
    }
    __syncthreads();
#pragma unroll
    for (int cc = 0; cc < 16; ++cc) {
      const float4 a0 = *(const float4*)&s_a[cc][tn];
      const float4 a1 = *(const float4*)&s_a[cc][tn + 4];
      const float4 b0 = *(const float4*)&s_b[cc][tm];
      const float4 b1 = *(const float4*)&s_b[cc][tm + 4];
      const float aa[8] = {a0.x, a0.y, a0.z, a0.w, a1.x, a1.y, a1.z, a1.w};
      const float bb2[8] = {b0.x, b0.y, b0.z, b0.w, b1.x, b1.y, b1.z, b1.w};
#pragma unroll
      for (int i = 0; i < 8; ++i)
#pragma unroll
        for (int j = 0; j < 8; ++j) acc[i][j] = fmaf(aa[i], bb2[j], acc[i][j]);
    }
  }
  float xmv[8];
#pragma unroll
  for (int j = 0; j < 8; ++j) xmv[j] = s_xx[128 + tm + j];
  float* Db = D + ((size_t)b << 20);
#pragma unroll
  for (int i = 0; i < 8; ++i) {
    const float xxn = s_xx[tn + i];
    float4 o0v, o1v;
    o0v.x = 2.f * acc[i][0] - xxn - xmv[0];
    o0v.y = 2.f * acc[i][1] - xxn - xmv[1];
    o0v.z = 2.f * acc[i][2] - xxn - xmv[2];
    o0v.w = 2.f * acc[i][3] - xxn - xmv[3];
    o1v.x = 2.f * acc[i][4] - xxn - xmv[4];
    o1v.y = 2.f * acc[i][5] - xxn - xmv[5];
    o1v.z = 2.f * acc[i][6] - xxn - xmv[6];
    o1v.w = 2.f * acc[i][7] - xxn - xmv[7];
    float* row = &Db[(size_t)(tn0 + tn + i) * NN + tm0 + tm];
    *(float4*)row = o0v;
    *(float4*)(row + 4) = o1v;
  }
  if (tn0 != tm0) {                  // mirror write (identical expression)
#pragma unroll
    for (int j = 0; j < 8; ++j) {
      const float xmj = xmv[j];
      float m[8];
#pragma unroll
      for (int i = 0; i < 8; ++i)
        m[i] = 2.f * acc[i][j] - s_xx[tn + i] - xmj;
      float* row = &Db[(size_t)(tm0 + tm + j) * NN + tn0 + tn];
      *(float4*)row = make_float4(m[0], m[1], m[2], m[3]);
      *(float4*)(row + 4) = make_float4(m[4], m[5], m[6], m[7]);
    }
  }
}

// ---------------------------------------------------------------------------
// topk helpers (per-lane sorted top-4 queue, disjoint ascending col ranges)
// ---------------------------------------------------------------------------
__device__ __forceinline__ void tk_ins(float v, int i, float lv[4], int li[4]) {
  if (kbetter(v, i, lv[3], li[3])) {
    lv[3] = v; li[3] = i;
    if (kbetter(lv[3], li[3], lv[2], li[2])) {
      float tv = lv[2]; int ti = li[2];
      lv[2] = lv[3]; li[2] = li[3]; lv[3] = tv; li[3] = ti;
    }
    if (kbetter(lv[2], li[2], lv[1], li[1])) {
      float tv = lv[1]; int ti = li[1];
      lv[1] = lv[2]; li[1] = li[2]; lv[2] = tv; li[2] = ti;
    }
    if (kbetter(lv[1], li[1], lv[0], li[0])) {
      float tv = lv[0]; int ti = li[0];
      lv[0] = lv[1]; li[0] = li[1]; lv[1] = tv; li[1] = ti;
    }
  }
}

__device__ __forceinline__ void tk_build(const float* __restrict__ Dr, int base,
                                         unsigned mask, float lv[4], int li[4]) {
#pragma unroll
  for (int q = 0; q < 4; ++q) { lv[q] = -3.4e38f; li[q] = 0x7FFFFFFF; }
  const float4 a0 = *(const float4*)&Dr[base + 0];
  const float4 a1 = *(const float4*)&Dr[base + 4];
  const float4 a2 = *(const float4*)&Dr[base + 8];
  const float4 a3 = *(const float4*)&Dr[base + 12];
  const float vs[16] = {a0.x, a0.y, a0.z, a0.w, a1.x, a1.y, a1.z, a1.w,
                        a2.x, a2.y, a2.z, a2.w, a3.x, a3.y, a3.z, a3.w};
#pragma unroll
  for (int j = 0; j < 16; ++j)
    if (!((mask >> j) & 1u)) tk_ins(vs[j], base + j, lv, li);
}

// ---------------------------------------------------------------------------
// merged topk (blocks 0..2047) + gemm_uv (blocks 2048..)
// ---------------------------------------------------------------------------
template <int C, int O>
__global__ __launch_bounds__(256) void tg_kernel(
    const float* __restrict__ D, int* __restrict__ idxb,
    const float* __restrict__ xbase, int bstr, const float* __restrict__ WT,
    float* __restrict__ U, float* __restrict__ Vd) {
  constexpr int OT = O / 64;
  const int t = threadIdx.x;
  if (blockIdx.x < 2048) {
    const int lane = t & 63;
    const int row = blockIdx.x * 4 + (t >> 6);
    const float* Dr = D + ((size_t)row << 10);
    const int base = lane * 16;
    float lv[4]; int li[4];
    unsigned mask = 0;
    tk_build(Dr, base, 0u, lv, li);
    for (int kk = 0; kk < KNB; ++kk) {
      float bv = lv[0];
#pragma unroll
      for (int off = 1; off < 64; off <<= 1)
        bv = fmaxf(bv, __shfl_xor(bv, off, 64));
      const unsigned long long m = __ballot(lv[0] == bv);
      const int wl = __ffsll(m) - 1;
      const int bi = __shfl(li[0], wl, 64);
      if (lane == 0) idxb[row * KNB + kk] = bi;
      if (lane == wl) {
        mask |= 1u << (bi & 15);
        lv[0] = lv[1]; li[0] = li[1];
        lv[1] = lv[2]; li[1] = li[2];
        lv[2] = lv[3]; li[2] = li[3];
        lv[3] = -3.4e38f; li[3] = 0x7FFFFFFF;
        if (li[0] == 0x7FFFFFFF && __popc(mask) < 16)
          tk_build(Dr, base, mask, lv, li);   // rare rescan
      }
    }
    return;
  }
  // ---- gemm_uv part ----
  __shared__ __align__(16) float s_x[8][64];
  __shared__ __align__(16) float s_wn[8][64];
  __shared__ __align__(16) float s_wc[8][64];
  const int bx = blockIdx.x - 2048;
  const int b = bx / (16 * OT);
  const int r = bx % (16 * OT);
  const int n0 = (r / OT) * 64;
  const int o0 = (r % OT) * 64;
  const float* xb = xbase + (size_t)b * bstr;
  const int tn = (t >> 4) * 4;
  const int to = (t & 15) * 4;
  float accU[4][4] = {}, accC[4][4] = {};
  for (int c0 = 0; c0 < C; c0 += 8) {
    const int kc = (C - c0 < 8) ? (C - c0) : 8;
    for (int i = t; i < 8 * 64; i += 256) {
      const int cc = i >> 6, col = i & 63;
      const bool ok = cc < kc;
      s_x[cc][col]  = ok ? xb[(c0 + cc) * NN + n0 + col] : 0.f;
      s_wn[cc][col] = ok ? WT[(c0 + cc) * O + o0 + col] : 0.f;
      s_wc[cc][col] = ok ? WT[(C + c0 + cc) * O + o0 + col] : 0.f;
    }
    __syncthreads();
#pragma unroll
    for (int cc = 0; cc < 8; ++cc) {
      const float4 xv = *(const float4*)&s_x[cc][tn];
      const float4 wn = *(const float4*)&s_wn[cc][to];
      const float4 wc = *(const float4*)&s_wc[cc][to];
      const float xa[4] = {xv.x, xv.y, xv.z, xv.w};
      const float na[4] = {wn.x, wn.y, wn.z, wn.w};
      const float ca[4] = {wc.x, wc.y, wc.z, wc.w};
#pragma unroll
      for (int i = 0; i < 4; ++i)
#pragma unroll
        for (int j = 0; j < 4; ++j) {
          accU[i][j] = fmaf(xa[i], na[j], accU[i][j]);
          accC[i][j] = fmaf(xa[i], ca[j], accC[i][j]);
        }
    }
    __syncthreads();
  }
#pragma unroll
  for (int i = 0; i < 4; ++i) {
    const size_t base2 = ((size_t)(b << 10) + n0 + tn + i) * O + o0 + to;
    *(float4*)&U[base2] = make_float4(accU[i][0], accU[i][1], accU[i][2], accU[i][3]);
    *(float4*)&Vd[base2] = make_float4(accC[i][0] - accU[i][0], accC[i][1] - accU[i][1],
                                       accC[i][2] - accU[i][2], accC[i][3] - accU[i][3]);
  }
}

// ---------------------------------------------------------------------------
// edge gather pass v2: thread owns an o-quad; y_k = U[b,idx_k,o..o+3]+Vd.
// PSUB points in flight per block; float4 loads throughout.
// ---------------------------------------------------------------------------
template <int O>
__global__ __launch_bounds__(256) void edge_pass_kernel(
    const float* __restrict__ U, const float* __restrict__ Vd,
    const int* __restrict__ idxb, float* __restrict__ stats,
    float* __restrict__ ymax, float* __restrict__ ymin) {
  constexpr int OQ = O / 4;          // quads per point
  constexpr int PSUB = 256 / OQ;     // points in flight
  __shared__ __align__(16) float4 s_red[256];
  const int t = threadIdx.x;
  const int q = t & (OQ - 1);
  const int psub = t / OQ;
  const int o0 = q * 4;
  float4 s1 = make_float4(0.f, 0.f, 0.f, 0.f);
  float4 s2 = make_float4(0.f, 0.f, 0.f, 0.f);
  for (int p = blockIdx.x * PSUB + psub; p < BB * NN; p += gridDim.x * PSUB) {
    const int b = p >> 10;
    const float* ub = U + ((size_t)(b << 10)) * O + o0;
    int id[KNB];
#pragma unroll
    for (int k = 0; k < KNB; ++k) id[k] = idxb[p * KNB + k];
    const float4 vd = *(const float4*)&Vd[(size_t)p * O + o0];
    float4 mx = make_float4(-3.4e38f, -3.4e38f, -3.4e38f, -3.4e38f);
    float4 mn = make_float4(3.4e38f, 3.4e38f, 3.4e38f, 3.4e38f);
#pragma unroll
    for (int k = 0; k < KNB; ++k) {
      const float4 u = *(const float4*)&ub[(size_t)id[k] * O];
      const float y0 = u.x + vd.x, y1 = u.y + vd.y;
      const float y2 = u.z + vd.z, y3 = u.w + vd.w;
      mx.x = fmaxf(mx.x, y0); mn.x = fminf(mn.x, y0);
      mx.y = fmaxf(mx.y, y1); mn.y = fminf(mn.y, y1);
      mx.z = fmaxf(mx.z, y2); mn.z = fminf(mn.z, y2);
      mx.w = fmaxf(mx.w, y3); mn.w = fminf(mn.w, y3);
      s1.x += y0; s1.y += y1; s1.z += y2; s1.w += y3;
      s2.x = fmaf(y0, y0, s2.x); s2.y = fmaf(y1, y1, s2.y);
      s2.z = fmaf(y2, y2, s2.z); s2.w = fmaf(y3, y3, s2.w);
    }
    *(float4*)&ymax[(size_t)p * O + o0] = mx;
    *(float4*)&ymin[(size_t)p * O + o0] = mn;
  }
  s_red[t] = s1;
  __syncthreads();
  if (t < OQ) {
    float4 s = s_red[t];
#pragma unroll
    for (int r2 = 1; r2 < PSUB; ++r2) {
      const float4 v = s_red[t + r2 * OQ];
      s.x += v.x; s.y += v.y; s.z += v.z; s.w += v.w;
    }
    atomicAdd(&stats[t * 4 + 0], s.x);
    atomicAdd(&stats[t * 4 + 1], s.y);
    atomicAdd(&stats[t * 4 + 2], s.z);
    atomicAdd(&stats[t * 4 + 3], s.w);
  }
  __syncthreads();
  s_red[t] = s2;
  __syncthreads();
  if (t < OQ) {
    float4 s = s_red[t];
#pragma unroll
    for (int r2 = 1; r2 < PSUB; ++r2) {
      const float4 v = s_red[t + r2 * OQ];
      s.x += v.x; s.y += v.y; s.z += v.z; s.w += v.w;
    }
    atomicAdd(&stats[1024 + t * 4 + 0], s.x);
    atomicAdd(&stats[1024 + t * 4 + 1], s.y);
    atomicAdd(&stats[1024 + t * 4 + 2], s.z);
    atomicAdd(&stats[1024 + t * 4 + 3], s.w);
  }
}

// ---------------------------------------------------------------------------
// bn_apply (finalize inlined) + transpose; packed bf16 write for conv1d MFMA.
// ---------------------------------------------------------------------------
template <int O>
__global__ __launch_bounds__(256) void bn_apply_kernel(
    const float* __restrict__ ymax, const float* __restrict__ ymin,
    const float* __restrict__ stats, const float* __restrict__ g,
    const float* __restrict__ bb, float* __restrict__ hout,
    unsigned short* __restrict__ hp, int coff) {
  constexpr int OT = O / 32;
  __shared__ float s_t[32][33];
  const int t = threadIdx.x;
  const int bx = blockIdx.x;
  const int b = bx / (32 * OT);
  const int r = bx % (32 * OT);
  const int n0 = (r / OT) * 32;
  const int o0 = (r % OT) * 32;
  const int col = t & 31, rowb = t >> 5;
  const int o = o0 + col;
  const float inv = 1.f / (8.f * 1024.f * 20.f);
  const float mean = stats[o] * inv;
  const float var = stats[1024 + o] * inv - mean * mean;
  const float sc = g[o] * rsqrtf(var + BNEPS);
  const float sh = bb[o] - mean * sc;
  const float* src = (sc >= 0.f) ? ymax : ymin;
  const int c = coff + o;               // conv1d K index
#pragma unroll
  for (int rr = 0; rr < 4; ++rr) {
    const int nl = n0 + rowb + rr * 8;
    const float y = src[((size_t)(b << 10) + nl) * O + o];
    const float h = lrelu(fmaf(sc, y, sh));
    s_t[rowb + rr * 8][col] = h;
    if (hp) {
      const int lane2 = (nl & 31) + ((c >> 3) & 1) * 32;
      hp[(((size_t)(b * 32 + (nl >> 5)) * 32 + (c >> 4)) * 64 + lane2) * 8 +
         (c & 7)] = f2b(h);
    }
  }
  __syncthreads();
#pragma unroll
  for (int rr = 0; rr < 4; ++rr) {
    const int ol = rowb + rr * 8;
    hout[(size_t)b * (512 * 1024) + (o0 + ol) * NN + n0 + col] = s_t[col][ol];
  }
}

// ---------------------------------------------------------------------------
// conv1d via MFMA on packed fragments: Y5[b][o][n] = sum_c W5[o][c]*h[b][n][c]
// ---------------------------------------------------------------------------
__global__ __launch_bounds__(256) void conv1d_mfma_kernel(
    const unsigned short* __restrict__ hp,
    const unsigned short* __restrict__ w5p, float* __restrict__ Y5) {
  const int t = threadIdx.x, bx = blockIdx.x;
  const int b = bx >> 6;
  const int r = bx & 63;
  const int w = t >> 6, lane = t & 63;
  const int ot0 = (r >> 3) * 4 + (w & 1) * 2;
  const int nt0 = (r & 7) * 4 + (w >> 1) * 2;
  const unsigned short* a0p = w5p + (size_t)ot0 * 16384 + lane * 8;
  const unsigned short* a1p = a0p + 16384;
  const unsigned short* b0p = hp + (size_t)(b * 32 + nt0) * 16384 + lane * 8;
  const unsigned short* b1p = b0p + 16384;
  f32x16 acc00, acc01, acc10, acc11;
#pragma unroll
  for (int i = 0; i < 16; ++i) { acc00[i] = 0.f; acc01[i] = 0.f; acc10[i] = 0.f; acc11[i] = 0.f; }
#pragma unroll 2
  for (int kb = 0; kb < 32; ++kb) {
    const int off = kb * 512;
    const short8v a0 = *(const short8v*)(a0p + off);
    const short8v a1 = *(const short8v*)(a1p + off);
    const short8v b0 = *(const short8v*)(b0p + off);
    const short8v b1 = *(const short8v*)(b1p + off);
    acc00 = __builtin_amdgcn_mfma_f32_32x32x16_bf16(a0, b0, acc00, 0, 0, 0);
    acc01 = __builtin_amdgcn_mfma_f32_32x32x16_bf16(a0, b1, acc01, 0, 0, 0);
    acc10 = __builtin_amdgcn_mfma_f32_32x32x16_bf16(a1, b0, acc10, 0, 0, 0);
    acc11 = __builtin_amdgcn_mfma_f32_32x32x16_bf16(a1, b1, acc11, 0, 0, 0);
  }
  const int l31 = lane & 31, l5 = lane >> 5;
#pragma unroll
  for (int oi = 0; oi < 2; ++oi) {
#pragma unroll
    for (int nj = 0; nj < 2; ++nj) {
      const f32x16 a = (oi == 0) ? (nj == 0 ? acc00 : acc01)
                                 : (nj == 0 ? acc10 : acc11);
      const int ob = (ot0 + oi) * 32;
      const int nb = (nt0 + nj) * 32;
#pragma unroll
      for (int r16 = 0; r16 < 16; ++r16) {
        const int row = (r16 & 3) + 8 * (r16 >> 2) + 4 * l5;
        Y5[((size_t)(b << 10) + ob + row) * 1024 + nb + l31] = a[r16];
      }
    }
  }
}

// ---------------------------------------------------------------------------
// fused conv1d BN stats + finalize + pool: one block per channel o.
// ---------------------------------------------------------------------------
__global__ __launch_bounds__(256) void c1pool_kernel(
    const float* __restrict__ Y5, const float* __restrict__ g,
    const float* __restrict__ bb, float* __restrict__ z) {
  __shared__ float sr[256];
  __shared__ float s_par[2];
  const int o = blockIdx.x, t = threadIdx.x;
  float s1 = 0.f, s2 = 0.f;
#pragma unroll
  for (int b = 0; b < 8; ++b) {
    const float4 v = *(const float4*)&Y5[((size_t)((b << 10) + o)) * 1024 + t * 4];
    s1 += v.x + v.y + v.z + v.w;
    s2 = fmaf(v.x, v.x, s2);
    s2 = fmaf(v.y, v.y, s2);
    s2 = fmaf(v.z, v.z, s2);
    s2 = fmaf(v.w, v.w, s2);
  }
  sr[t] = s1;
  __syncthreads();
  for (int s = 128; s > 0; s >>= 1) {
    if (t < s) sr[t] += sr[t + s];
    __syncthreads();
  }
  if (t == 0) s_par[0] = sr[0];
  __syncthreads();
  sr[t] = s2;
  __syncthreads();
  for (int s = 128; s > 0; s >>= 1) {
    if (t < s) sr[t] += sr[t + s];
    __syncthreads();
  }
  if (t == 0) {
    const float mean = s_par[0] * (1.f / 8192.f);
    const float var = sr[0] * (1.f / 8192.f) - mean * mean;
    const float sc = g[o] * rsqrtf(var + BNEPS);
    s_par[0] = sc;
    s_par[1] = bb[o] - mean * sc;
  }
  __syncthreads();
  const float sc = s_par[0], sh = s_par[1];
  const int lane = t & 63, w = t >> 6;
#pragma unroll
  for (int h = 0; h < 2; ++h) {
    const int b = w + h * 4;
    const float* yr = Y5 + ((size_t)((b << 10) + o)) * 1024 + lane * 16;
    float mx = -3.4e38f, sm = 0.f;
#pragma unroll
    for (int j = 0; j < 4; ++j) {
      const float4 v = *(const float4*)&yr[j * 4];
      const float y0 = lrelu(fmaf(sc, v.x, sh));
      const float y1 = lrelu(fmaf(sc, v.y, sh));
      const float y2 = lrelu(fmaf(sc, v.z, sh));
      const float y3 = lrelu(fmaf(sc, v.w, sh));
      mx = fmaxf(fmaxf(fmaxf(mx, y0), fmaxf(y1, y2)), y3);
      sm += y0 + y1 + y2 + y3;
    }
#pragma unroll
    for (int off = 1; off < 64; off <<= 1) {
      mx = fmaxf(mx, __shfl_xor(mx, off, 64));
      sm += __shfl_xor(sm, off, 64);
    }
    if (lane == 0) {
      z[b * 2048 + o] = mx;
      z[b * 2048 + 1024 + o] = sm * (1.f / 1024.f);
    }
  }
}

// ---------------------------------------------------------------------------
// fallback f32 conv1d (used only if ws too small for MFMA buffers)
// ---------------------------------------------------------------------------
__global__ void bn_finalize_kernel(float* __restrict__ stats,
                                   const float* __restrict__ g,
                                   const float* __restrict__ bb, int cout,
                                   float inv_cnt) {
  const int o = blockIdx.x * 256 + threadIdx.x;
  if (o >= cout) return;
  const float mean = stats[o] * inv_cnt;
  const float var = stats[1024 + o] * inv_cnt - mean * mean;
  const float s = g[o] * rsqrtf(var + BNEPS);
  stats[2048 + o] = s;
  stats[3072 + o] = bb[o] - mean * s;
}

__global__ __launch_bounds__(256) void conv1d_gemm_kernel(
    const float* __restrict__ hcat, const float* __restrict__ WT5,
    float* __restrict__ stats, float* __restrict__ Y5) {
  __shared__ __align__(16) float s_w[8][64];
  __shared__ __align__(16) float s_h[8][64];
  __shared__ __align__(16) float s_red[64][16];
  const int t = threadIdx.x;
  const int bx = blockIdx.x;
  const int b = bx >> 8;
  const int o0 = ((bx >> 4) & 15) * 64;
  const int n0 = (bx & 15) * 64;
  const float* hb = hcat + (size_t)b * (512 * 1024);
  const int to = (t >> 4) * 4;
  const int tn = (t & 15) * 4;
  float acc[4][4] = {};
  for (int c0 = 0; c0 < 512; c0 += 8) {
    for (int i = t; i < 8 * 64; i += 256) {
      const int cc = i >> 6, col = i & 63;
      s_w[cc][col] = WT5[(c0 + cc) * 1024 + o0 + col];
      s_h[cc][col] = hb[(c0 + cc) * NN + n0 + col];
    }
    __syncthreads();
#pragma unroll
    for (int cc = 0; cc < 8; ++cc) {
      const float4 wv = *(const float4*)&s_w[cc][to];
      const float4 hv = *(const float4*)&s_h[cc][tn];
      const float wa[4] = {wv.x, wv.y, wv.z, wv.w};
      const float ha[4] = {hv.x, hv.y, hv.z, hv.w};
#pragma unroll
      for (int i = 0; i < 4; ++i)
#pragma unroll
        for (int j = 0; j < 4; ++j) acc[i][j] = fmaf(wa[i], ha[j], acc[i][j]);
    }
    __syncthreads();
  }
#pragma unroll
  for (int i = 0; i < 4; ++i) {
    *(float4*)&Y5[((size_t)(b << 10) + o0 + to + i) * NN + n0 + tn] =
        make_float4(acc[i][0], acc[i][1], acc[i][2], acc[i][3]);
  }
#pragma unroll
  for (int i = 0; i < 4; ++i)
    s_red[to + i][t & 15] = acc[i][0] + acc[i][1] + acc[i][2] + acc[i][3];
  __syncthreads();
  if (t < 64) {
    float s = 0.f;
#pragma unroll
    for (int g2 = 0; g2 < 16; ++g2) s += s_red[t][g2];
    atomicAdd(&stats[o0 + t], s);
  }
  __syncthreads();
#pragma unroll
  for (int i = 0; i < 4; ++i) {
    float s = 0.f;
#pragma unroll
    for (int j = 0; j < 4; ++j) s = fmaf(acc[i][j], acc[i][j], s);
    s_red[to + i][t & 15] = s;
  }
  __syncthreads();
  if (t < 64) {
    float s = 0.f;
#pragma unroll
    for (int g2 = 0; g2 < 16; ++g2) s += s_red[t][g2];
    atomicAdd(&stats[1024 + o0 + t], s);
  }
}

__global__ __launch_bounds__(256) void pool_kernel(
    const float* __restrict__ Y5, const float* __restrict__ stats,
    float* __restrict__ z) {
  const int t = threadIdx.x;
  const int lane = t & 63;
  const int bx = blockIdx.x;
  const int b = bx >> 8;
  const int o = (bx & 255) * 4 + (t >> 6);
  const float sc = stats[2048 + o], sh = stats[3072 + o];
  const float* yr = Y5 + ((size_t)(b << 10) + o) * NN;
  float mx = -3.4e38f, sm = 0.f;
#pragma unroll
  for (int j = 0; j < 16; ++j) {
    const float y = lrelu(fmaf(sc, yr[j * 64 + lane], sh));
    mx = fmaxf(mx, y);
    sm += y;
  }
  for (int off = 32; off > 0; off >>= 1) {
    mx = fmaxf(mx, __shfl_down(mx, off, 64));
    sm += __shfl_down(sm, off, 64);
  }
  if (lane == 0) {
    z[b * 2048 + o] = mx;
    z[b * 2048 + 1024 + o] = sm * (1.f / 1024.f);
  }
}

// ---------------------------------------------------------------------------
// MLP layer with batch-of-8 BN + lrelu fused.
// ---------------------------------------------------------------------------
__global__ __launch_bounds__(256) void mlp_kernel(
    const float* __restrict__ zin, const float* __restrict__ W,
    const float* __restrict__ bias, const float* __restrict__ g,
    const float* __restrict__ bb, int kin, float* __restrict__ out, int O) {
  __shared__ float s_red[256];
  __shared__ float s_y[8];
  const int t = threadIdx.x;
  const int o = blockIdx.x;
  float acc[8];
#pragma unroll
  for (int b = 0; b < 8; ++b) acc[b] = 0.f;
  for (int c = t; c < kin; c += 256) {
    const float w = W[(size_t)o * kin + c];
#pragma unroll
    for (int b = 0; b < 8; ++b) acc[b] = fmaf(w, zin[b * kin + c], acc[b]);
  }
  for (int b = 0; b < 8; ++b) {
    s_red[t] = acc[b];
    __syncthreads();
    for (int s = 128; s > 0; s >>= 1) {
      if (t < s) s_red[t] += s_red[t + s];
      __syncthreads();
    }
    if (t == 0) s_y[b] = s_red[0] + (bias ? bias[o] : 0.f);
    __syncthreads();
  }
  if (t == 0) {
    float m = 0.f;
    for (int b = 0; b < 8; ++b) m += s_y[b];
    m *= 0.125f;
    float v = 0.f;
    for (int b = 0; b < 8; ++b) { const float d = s_y[b] - m; v = fmaf(d, d, v); }
    v *= 0.125f;
    const float s = g[o] * rsqrtf(v + BNEPS);
    const float sh = bb[o] - m * s;
    for (int b = 0; b < 8; ++b) out[b * O + o] = lrelu(fmaf(s, s_y[b], sh));
  }
}

// final: out = z2 @ Wl3^T + bl3; output dtype derived from flags here.
__global__ void final_kernel(const float* __restrict__ z2,
                             const float* __restrict__ Wl3,
                             const float* __restrict__ bl3,
                             const int* __restrict__ flags, void* out) {
  const int j = blockIdx.x * 256 + threadIdx.x;
  if (j >= 320) return;
  int anyf32 = 0, anybf = 0;
  for (int i = 0; i < NIN; ++i) {
    const int fl = flags[i];
    if (fl == 0) anyf32 = 1;
    if (fl == 1) anybf = 1;
  }
  const int bf16out = (anybf && !anyf32) ? 1 : 0;
  const int b = j / 40, o = j - b * 40;
  float s = bl3[o];
  for (int c = 0; c < 256; ++c) s = fmaf(z2[b * 256 + c], Wl3[o * 256 + c], s);
  if (bf16out) ((__hip_bfloat16*)out)[j] = __float2bfloat16(s);
  else ((float*)out)[j] = s;
}

// ---------------------------------------------------------------------------
template <int C, int O>
static void run_stage(float* wsf, const float* xbase, int bstr, int widx,
                      int gidx, int bidx, int stat, float* hout,
                      unsigned short* hp, int coff, hipStream_t stream) {
  int* idxb = reinterpret_cast<int*>(wsf + IDXo);
  float* dist = wsf + DISTo;
  float* U = wsf + U_OFF;
  float* Vd = wsf + VD_OFF;
  float* ymx = wsf + YMX_OFF;
  float* ymn = wsf + YMN_OFF;
  float* stats = wsf + STATSo + stat * 4096;
  dist2_kernel<C><<<BB * 36, 256, 0, stream>>>(xbase, bstr, dist);
  tg_kernel<C, O><<<2048 + BB * 16 * (O / 64), 256, 0, stream>>>(
      dist, idxb, xbase, bstr, wsf + widx, U, Vd);
  edge_pass_kernel<O><<<512, 256, 0, stream>>>(U, Vd, idxb, stats, ymx, ymn);
  bn_apply_kernel<O><<<BB * 32 * (O / 32), 256, 0, stream>>>(
      ymx, ymn, stats, wsf + gidx, wsf + bidx, hout, hp, coff);
}

extern "C" void kernel_launch(void* const* d_in, const int* in_sizes, int n_in,
                              void* d_out, int out_size, void* d_ws,
                              size_t ws_size, hipStream_t stream) {
  (void)in_sizes; (void)n_in; (void)out_size;
  float* wsf = reinterpret_cast<float*>(d_ws);
  int* flags = reinterpret_cast<int*>(wsf + FLAGSo);
  float* hcat = wsf + HCATo;
  const bool mf = ws_size >= WS_NEED_MFMA;
  unsigned short* hp = mf ? reinterpret_cast<unsigned short*>(wsf + HBFo) : nullptr;
  unsigned short* w5p = reinterpret_cast<unsigned short*>(wsf + W5BFo);

  Ptrs ptrs;
  for (int i = 0; i < NIN; ++i) ptrs.p[i] = d_in[i];

  detect_kernel<<<NIN, 64, 0, stream>>>(ptrs, flags);
  convert_kernel<<<NCONV + 80 + 256, 256, 0, stream>>>(ptrs, flags, wsf,
                                                       mf ? 1 : 0);

  run_stage<3, 64>(wsf, wsf + XIN, 3 * NN, WT1, G1, B1o, 0, hcat, hp, 0,
                   stream);
  run_stage<64, 64>(wsf, hcat, 512 * NN, WT2, G2, B2o, 1, hcat + 64 * NN, hp,
                    64, stream);
  run_stage<64, 128>(wsf, hcat + 64 * NN, 512 * NN, WT3, G3, B3o, 2,
                     hcat + 128 * NN, hp, 128, stream);
  run_stage<128, 256>(wsf, hcat + 128 * NN, 512 * NN, WT4, G4, B4o, 3,
                      hcat + 256 * NN, hp, 256, stream);

  // conv1d 512->1024 + BN + pool
  float* Y5 = wsf + Y5_OFF;
  float* st5 = wsf + STATSo + 4 * 4096;
  if (mf) {
    conv1d_mfma_kernel<<<512, 256, 0, stream>>>(hp, w5p, Y5);
    c1pool_kernel<<<1024, 256, 0, stream>>>(Y5, wsf + G5, wsf + B5o,
                                            wsf + Z2048o);
  } else {
    conv1d_gemm_kernel<<<2048, 256, 0, stream>>>(hcat, wsf + WT5, st5, Y5);
    bn_finalize_kernel<<<4, 256, 0, stream>>>(st5, wsf + G5, wsf + B5o, 1024,
                                              1.f / 8192.f);
    pool_kernel<<<BB * 256, 256, 0, stream>>>(Y5, st5, wsf + Z2048o);
  }

  // MLP head
  mlp_kernel<<<512, 256, 0, stream>>>(wsf + Z2048o, wsf + WL1, nullptr,
      wsf + G6, wsf + B6o, 2048, wsf + Z1o, 512);
  mlp_kernel<<<256, 256, 0, stream>>>(wsf + Z1o, wsf + WL2, wsf + BL2o,
      wsf + G7, wsf + B7o, 512, wsf + Z2o, 256);
  final_kernel<<<2, 256, 0, stream>>>(wsf + Z2o, wsf + WL3, wsf + BL3o,
      flags, d_out);
}

// Round 12
// 548.433 us; speedup vs baseline: 1.1988x; 1.1988x over previous
//
#include <hip/hip_runtime.h>
#include <hip/hip_bf16.h>
#include <cstdint>

// ---------------------------------------------------------------------------
// DGCNN forward on MI355X. Math f32; conv1d via bf16 MFMA on packed
// fragment layouts; kNN via symmetric dist GEMM + register-queue wave top-k.
// R12: edge_pass reverted to R10 v1 (scalar gather = max memory-level
// parallelism; R11's float4 variant cut outstanding misses 4x and ran 4x
// slower), grid doubled to 1024 for more in-flight loads. Symmetric dist2
// (R11's win) retained.
// ---------------------------------------------------------------------------

static constexpr int BB  = 8;
static constexpr int NN  = 1024;
static constexpr int KNB = 20;
static constexpr float BNEPS = 1e-5f;

static constexpr int NIN = 25;

__constant__ int c_cum[NIN + 1] = {
    0, 24576, 24960, 33152, 49536, 115072, 639360,
    1687936, 1819008, 1819264, 1829504, 1829544, 1829608, 1829672, 1829736,
    1829800, 1829928, 1830056, 1830312, 1830568, 1831592, 1832616, 1833128,
    1833640, 1833896, 1834152};
__constant__ int c_trO[NIN] = {0, 64, 64, 128, 256, 1024, 0, 0, 0, 0, 0,
                               0, 0, 0, 0, 0, 0, 0, 0, 0, 0, 0, 0, 0, 0};
__constant__ int c_trI[NIN] = {0, 6, 128, 128, 256, 512, 0, 0, 0, 0, 0,
                               0, 0, 0, 0, 0, 0, 0, 0, 0, 0, 0, 0, 0, 0};
// upper-triangle 128-tile pairs (rn <= rm), 36 of them
__constant__ int c_trn[36] = {0,0,0,0,0,0,0,0, 1,1,1,1,1,1,1, 2,2,2,2,2,2,
                              3,3,3,3,3, 4,4,4,4, 5,5,5, 6,6, 7};
__constant__ int c_trm[36] = {0,1,2,3,4,5,6,7, 1,2,3,4,5,6,7, 2,3,4,5,6,7,
                              3,4,5,6,7, 4,5,6,7, 5,6,7, 6,7, 7};

enum : int {
  XIN = 0, WT1 = 24576, WT2 = 24960, WT3 = 33152, WT4 = 49536, WT5 = 115072,
  WL1 = 639360, WL2 = 1687936, BL2o = 1819008, WL3 = 1819264, BL3o = 1829504,
  G1 = 1829544, B1o = 1829608, G2 = 1829672, B2o = 1829736,
  G3 = 1829800, B3o = 1829928, G4 = 1830056, B4o = 1830312,
  G5 = 1830568, B5o = 1831592, G6 = 1832616, B6o = 1833128,
  G7 = 1833640, B7o = 1833896,
  IDXo = 1842432,       // 163840 i32
  HCATo = 2006272,      // 8*512*1024 f
  STATSo = 6200576,     // 5 layers * 4096 f
  Z2048o = 6237440,     // 8*2048 f
  Z1o = 6253824,        // 8*512 f
  Z2o = 6257920,        // 8*256 f
  FLAGSo = 6259968,     // 32 i32
  DISTo = 6260736,      // 8M-float window (sequentially reused)
  HBFo  = 14649344,     // packed bf16 h: 8*1024*512 shorts (2M float slots)
  W5BFo = 16746496      // packed bf16 w5: 512K shorts -> ends 17008640
};
static constexpr int TOTAL_IN = 1834152;
static constexpr int NCONV = (TOTAL_IN + 255) / 256;   // 7165 blocks
static constexpr int U_OFF   = DISTo + 0;
static constexpr int VD_OFF  = DISTo + 2097152;
static constexpr int YMX_OFF = DISTo + 4194304;
static constexpr int YMN_OFF = DISTo + 6291456;
static constexpr int Y5_OFF  = DISTo + 0;
static constexpr size_t WS_NEED_MFMA = (size_t)17008640 * 4;  // ~68 MB

struct Ptrs { const void* p[NIN]; };

typedef short short8v __attribute__((ext_vector_type(8)));
typedef float f32x16 __attribute__((ext_vector_type(16)));

__device__ __forceinline__ float lrelu(float y) { return (y < 0.f) ? 0.2f * y : y; }
__device__ __forceinline__ unsigned short f2b(float f) {
  unsigned u = __float_as_uint(f);
  unsigned r = (u + 0x7FFFu + ((u >> 16) & 1u)) >> 16;   // RNE
  return (unsigned short)r;
}
__device__ __forceinline__ bool kbetter(float v, int i, float v2, int i2) {
  return v > v2 || (v == v2 && i < i2);
}
__device__ __forceinline__ float load_in(const void* p, int fl, int idx) {
  if (fl == 2) return 0.f;
  if (fl == 1) {
    const unsigned short u = ((const unsigned short*)p)[idx];
    return __uint_as_float(((unsigned)u) << 16);
  }
  return ((const float*)p)[idx];
}

// ---------------------------------------------------------------------------
// dtype detection
// ---------------------------------------------------------------------------
__global__ void detect_kernel(Ptrs ptrs, int* __restrict__ flags) {
  const int i = blockIdx.x;
  const unsigned* p = (const unsigned*)ptrs.p[i];
  const int n = c_cum[i + 1] - c_cum[i];
  int words = n >> 1; if (words > 64) words = 64;
  const int t = threadIdx.x;
  unsigned w = (t < words) ? p[t] : 0u;
  bool nz = (w != 0u);
  unsigned e = (w >> 7) & 0xFFu;
  bool pl = nz && (e >= 96u) && (e <= 140u);
  unsigned long long mnz = __ballot(nz);
  unsigned long long mpl = __ballot(pl);
  if (t == 0) {
    int cnz = __popcll(mnz), cpl = __popcll(mpl);
    flags[i] = (cnz == 0) ? 2 : ((2 * cpl > words) ? 1 : 0);
  }
}

// ---------------------------------------------------------------------------
// convert: main blocks convert+transpose inputs; tail1 zeroes stats;
// tail2 packs w5 (raw input -> MFMA A-fragment bf16) if do_w5.
// ---------------------------------------------------------------------------
__global__ void convert_kernel(Ptrs ptrs, const int* __restrict__ flags,
                               float* __restrict__ ws, int do_w5) {
  const int bx = blockIdx.x;
  const int t = threadIdx.x;
  if (bx >= NCONV + 80) {            // tail2: w5 packing
    if (!do_w5) return;
    const int g = (bx - NCONV - 80) * 256 + t;   // 0..65535
    const int lane = g & 63;
    const int kb = (g >> 6) & 31;
    const int ot = g >> 11;
    const int o = ot * 32 + (lane & 31);
    const int k0 = kb * 16 + (lane >> 5) * 8;
    const void* w5raw = ptrs.p[5];
    const int fl = flags[5];
    unsigned u[4];
#pragma unroll
    for (int h = 0; h < 4; ++h) {
      const unsigned short lo = f2b(load_in(w5raw, fl, o * 512 + k0 + 2 * h));
      const unsigned short hi = f2b(load_in(w5raw, fl, o * 512 + k0 + 2 * h + 1));
      u[h] = (unsigned)lo | ((unsigned)hi << 16);
    }
    unsigned short* w5p = (unsigned short*)(ws + W5BFo);
    *(uint4*)&w5p[(size_t)g * 8] = make_uint4(u[0], u[1], u[2], u[3]);
    return;
  }
  if (bx >= NCONV) {                 // tail1: zero stats
    const int z = (bx - NCONV) * 256 + t;
    if (z < 20480) ws[STATSo + z] = 0.f;
    return;
  }
  const int e = bx * 256 + t;
  if (e >= TOTAL_IN) return;
  int i = 0;
  while (e >= c_cum[i + 1]) ++i;
  const int el = e - c_cum[i];
  int src;
  const int O = c_trO[i];
  if (O > 0) {
    const int I = c_trI[i];
    const int o = el % O, ii = el / O;
    src = o * I + ii;
  } else src = el;
  ws[e] = load_in(ptrs.p[i], flags[i], src);
}

// ---------------------------------------------------------------------------
// dist GEMM, symmetric: compute only rn<=rm 128x128 tiles (36/batch), mirror
// off-diagonal tiles with the identical expression (bitwise-symmetric D).
// ---------------------------------------------------------------------------
template <int C>
__global__ __launch_bounds__(256) void dist2_kernel(
    const float* __restrict__ xbase, int bstr, float* __restrict__ D) {
  __shared__ __align__(16) float s_a[16][128];
  __shared__ __align__(16) float s_b[16][128];
  __shared__ float s_xx[256];
  const int t = threadIdx.x;
  const int bx = blockIdx.x;
  const int b = bx / 36;
  const int r = bx % 36;
  const int tn0 = c_trn[r] * 128;
  const int tm0 = c_trm[r] * 128;
  const float* xb = xbase + (size_t)b * bstr;
  {
    const int idx = (t < 128) ? (tn0 + t) : (tm0 + (t - 128));
    float s = 0.f;
    for (int c = 0; c < C; ++c) {
      const float v = xb[c * NN + idx];
      s = fmaf(v, v, s);
    }
    s_xx[t] = s;
  }
  const int tn = (t >> 4) * 8;
  const int tm = (t & 15) * 8;
  float acc[8][8] = {};
  for (int c0 = 0; c0 < C; c0 += 16) {
    const int kc = (C - c0 < 16) ? (C - c0) : 16;
    __syncthreads();
    for (int i = t; i < 512; i += 256) {
      const int cc = i >> 5, col4 = (i & 31) * 4;
      float4 va = make_float4(0.f, 0.f, 0.f, 0.f), vb = va;
      if (cc < kc) {
        va = *(const float4*)&xb[(c0 + cc) * NN + tn0 + col4];
        vb = *(const float4*)&xb[(c0 + cc) * NN + tm0 + col4];
      }
      *(float4*)&s_a[cc][col4] = va;
      *(float4*)&s_b[cc][col4] = vb;
    }
    __syncthreads();
#pragma unroll
    for (int cc = 0; cc < 16; ++cc) {
      const float4 a0 = *(const float4*)&s_a[cc][tn];
      const float4 a1 = *(const float4*)&s_a[cc][tn + 4];
      const float4 b0 = *(const float4*)&s_b[cc][tm];
      const float4 b1 = *(const float4*)&s_b[cc][tm + 4];
      const float aa[8] = {a0.x, a0.y, a0.z, a0.w, a1.x, a1.y, a1.z, a1.w};
      const float bb2[8] = {b0.x, b0.y, b0.z, b0.w, b1.x, b1.y, b1.z, b1.w};
#pragma unroll
      for (int i = 0; i < 8; ++i)
#pragma unroll
        for (int j = 0; j < 8; ++j) acc[i][j] = fmaf(aa[i], bb2[j], acc[i][j]);
    }
  }
  float xmv[8];
#pragma unroll
  for (int j = 0; j < 8; ++j) xmv[j] = s_xx[128 + tm + j];
  float* Db = D + ((size_t)b << 20);
#pragma unroll
  for (int i = 0; i < 8; ++i) {
    const float xxn = s_xx[tn + i];
    float4 o0v, o1v;
    o0v.x = 2.f * acc[i][0] - xxn - xmv[0];
    o0v.y = 2.f * acc[i][1] - xxn - xmv[1];
    o0v.z = 2.f * acc[i][2] - xxn - xmv[2];
    o0v.w = 2.f * acc[i][3] - xxn - xmv[3];
    o1v.x = 2.f * acc[i][4] - xxn - xmv[4];
    o1v.y = 2.f * acc[i][5] - xxn - xmv[5];
    o1v.z = 2.f * acc[i][6] - xxn - xmv[6];
    o1v.w = 2.f * acc[i][7] - xxn - xmv[7];
    float* row = &Db[(size_t)(tn0 + tn + i) * NN + tm0 + tm];
    *(float4*)row = o0v;
    *(float4*)(row + 4) = o1v;
  }
  if (tn0 != tm0) {                  // mirror write (identical expression)
#pragma unroll
    for (int j = 0; j < 8; ++j) {
      const float xmj = xmv[j];
      float m[8];
#pragma unroll
      for (int i = 0; i < 8; ++i)
        m[i] = 2.f * acc[i][j] - s_xx[tn + i] - xmj;
      float* row = &Db[(size_t)(tm0 + tm + j) * NN + tn0 + tn];
      *(float4*)row = make_float4(m[0], m[1], m[2], m[3]);
      *(float4*)(row + 4) = make_float4(m[4], m[5], m[6], m[7]);
    }
  }
}

// ---------------------------------------------------------------------------
// topk helpers (per-lane sorted top-4 queue, disjoint ascending col ranges)
// ---------------------------------------------------------------------------
__device__ __forceinline__ void tk_ins(float v, int i, float lv[4], int li[4]) {
  if (kbetter(v, i, lv[3], li[3])) {
    lv[3] = v; li[3] = i;
    if (kbetter(lv[3], li[3], lv[2], li[2])) {
      float tv = lv[2]; int ti = li[2];
      lv[2] = lv[3]; li[2] = li[3]; lv[3] = tv; li[3] = ti;
    }
    if (kbetter(lv[2], li[2], lv[1], li[1])) {
      float tv = lv[1]; int ti = li[1];
      lv[1] = lv[2]; li[1] = li[2]; lv[2] = tv; li[2] = ti;
    }
    if (kbetter(lv[1], li[1], lv[0], li[0])) {
      float tv = lv[0]; int ti = li[0];
      lv[0] = lv[1]; li[0] = li[1]; lv[1] = tv; li[1] = ti;
    }
  }
}

__device__ __forceinline__ void tk_build(const float* __restrict__ Dr, int base,
                                         unsigned mask, float lv[4], int li[4]) {
#pragma unroll
  for (int q = 0; q < 4; ++q) { lv[q] = -3.4e38f; li[q] = 0x7FFFFFFF; }
  const float4 a0 = *(const float4*)&Dr[base + 0];
  const float4 a1 = *(const float4*)&Dr[base + 4];
  const float4 a2 = *(const float4*)&Dr[base + 8];
  const float4 a3 = *(const float4*)&Dr[base + 12];
  const float vs[16] = {a0.x, a0.y, a0.z, a0.w, a1.x, a1.y, a1.z, a1.w,
                        a2.x, a2.y, a2.z, a2.w, a3.x, a3.y, a3.z, a3.w};
#pragma unroll
  for (int j = 0; j < 16; ++j)
    if (!((mask >> j) & 1u)) tk_ins(vs[j], base + j, lv, li);
}

// ---------------------------------------------------------------------------
// merged topk (blocks 0..2047) + gemm_uv (blocks 2048..)
// ---------------------------------------------------------------------------
template <int C, int O>
__global__ __launch_bounds__(256) void tg_kernel(
    const float* __restrict__ D, int* __restrict__ idxb,
    const float* __restrict__ xbase, int bstr, const float* __restrict__ WT,
    float* __restrict__ U, float* __restrict__ Vd) {
  constexpr int OT = O / 64;
  const int t = threadIdx.x;
  if (blockIdx.x < 2048) {
    const int lane = t & 63;
    const int row = blockIdx.x * 4 + (t >> 6);
    const float* Dr = D + ((size_t)row << 10);
    const int base = lane * 16;
    float lv[4]; int li[4];
    unsigned mask = 0;
    tk_build(Dr, base, 0u, lv, li);
    for (int kk = 0; kk < KNB; ++kk) {
      float bv = lv[0];
#pragma unroll
      for (int off = 1; off < 64; off <<= 1)
        bv = fmaxf(bv, __shfl_xor(bv, off, 64));
      const unsigned long long m = __ballot(lv[0] == bv);
      const int wl = __ffsll(m) - 1;
      const int bi = __shfl(li[0], wl, 64);
      if (lane == 0) idxb[row * KNB + kk] = bi;
      if (lane == wl) {
        mask |= 1u << (bi & 15);
        lv[0] = lv[1]; li[0] = li[1];
        lv[1] = lv[2]; li[1] = li[2];
        lv[2] = lv[3]; li[2] = li[3];
        lv[3] = -3.4e38f; li[3] = 0x7FFFFFFF;
        if (li[0] == 0x7FFFFFFF && __popc(mask) < 16)
          tk_build(Dr, base, mask, lv, li);   // rare rescan
      }
    }
    return;
  }
  // ---- gemm_uv part ----
  __shared__ __align__(16) float s_x[8][64];
  __shared__ __align__(16) float s_wn[8][64];
  __shared__ __align__(16) float s_wc[8][64];
  const int bx = blockIdx.x - 2048;
  const int b = bx / (16 * OT);
  const int r = bx % (16 * OT);
  const int n0 = (r / OT) * 64;
  const int o0 = (r % OT) * 64;
  const float* xb = xbase + (size_t)b * bstr;
  const int tn = (t >> 4) * 4;
  const int to = (t & 15) * 4;
  float accU[4][4] = {}, accC[4][4] = {};
  for (int c0 = 0; c0 < C; c0 += 8) {
    const int kc = (C - c0 < 8) ? (C - c0) : 8;
    for (int i = t; i < 8 * 64; i += 256) {
      const int cc = i >> 6, col = i & 63;
      const bool ok = cc < kc;
      s_x[cc][col]  = ok ? xb[(c0 + cc) * NN + n0 + col] : 0.f;
      s_wn[cc][col] = ok ? WT[(c0 + cc) * O + o0 + col] : 0.f;
      s_wc[cc][col] = ok ? WT[(C + c0 + cc) * O + o0 + col] : 0.f;
    }
    __syncthreads();
#pragma unroll
    for (int cc = 0; cc < 8; ++cc) {
      const float4 xv = *(const float4*)&s_x[cc][tn];
      const float4 wn = *(const float4*)&s_wn[cc][to];
      const float4 wc = *(const float4*)&s_wc[cc][to];
      const float xa[4] = {xv.x, xv.y, xv.z, xv.w};
      const float na[4] = {wn.x, wn.y, wn.z, wn.w};
      const float ca[4] = {wc.x, wc.y, wc.z, wc.w};
#pragma unroll
      for (int i = 0; i < 4; ++i)
#pragma unroll
        for (int j = 0; j < 4; ++j) {
          accU[i][j] = fmaf(xa[i], na[j], accU[i][j]);
          accC[i][j] = fmaf(xa[i], ca[j], accC[i][j]);
        }
    }
    __syncthreads();
  }
#pragma unroll
  for (int i = 0; i < 4; ++i) {
    const size_t base2 = ((size_t)(b << 10) + n0 + tn + i) * O + o0 + to;
    *(float4*)&U[base2] = make_float4(accU[i][0], accU[i][1], accU[i][2], accU[i][3]);
    *(float4*)&Vd[base2] = make_float4(accC[i][0] - accU[i][0], accC[i][1] - accU[i][1],
                                       accC[i][2] - accU[i][2], accC[i][3] - accU[i][3]);
  }
}

// ---------------------------------------------------------------------------
// edge gather pass (R10 v1): scalar per-o loads = max outstanding misses.
// y_k = U[b,idx_k,o] + Vd[b,n,o]; ymax/ymin + BN sums.
// ---------------------------------------------------------------------------
template <int O>
__global__ __launch_bounds__(256) void edge_pass_kernel(
    const float* __restrict__ U, const float* __restrict__ Vd,
    const int* __restrict__ idxb, float* __restrict__ stats,
    float* __restrict__ ymax, float* __restrict__ ymin) {
  constexpr int PSUB = 256 / O;
  __shared__ float s_red[256];
  const int t = threadIdx.x;
  const int o = t & (O - 1);
  const int psub = t / O;
  float ls1 = 0.f, ls2 = 0.f;
  for (int p = blockIdx.x * PSUB + psub; p < BB * NN; p += gridDim.x * PSUB) {
    const int b = p >> 10;
    const float* ub = U + ((size_t)(b << 10)) * O;
    int id[KNB];
#pragma unroll
    for (int k = 0; k < KNB; ++k) id[k] = idxb[p * KNB + k];
    const float vd = Vd[(size_t)p * O + o];
    float ymx = -3.4e38f, ymn = 3.4e38f;
#pragma unroll
    for (int k = 0; k < KNB; ++k) {
      const float y = ub[(size_t)id[k] * O + o] + vd;
      ymx = fmaxf(ymx, y);
      ymn = fminf(ymn, y);
      ls1 += y;
      ls2 = fmaf(y, y, ls2);
    }
    ymax[(size_t)p * O + o] = ymx;
    ymin[(size_t)p * O + o] = ymn;
  }
  if (PSUB == 1) {
    atomicAdd(&stats[o], ls1);
    atomicAdd(&stats[1024 + o], ls2);
  } else {
    s_red[t] = ls1;
    __syncthreads();
    if (t < O) {
      float s = s_red[t];
#pragma unroll
      for (int p2 = 1; p2 < PSUB; ++p2) s += s_red[t + p2 * O];
      atomicAdd(&stats[t], s);
    }
    __syncthreads();
    s_red[t] = ls2;
    __syncthreads();
    if (t < O) {
      float s = s_red[t];
#pragma unroll
      for (int p2 = 1; p2 < PSUB; ++p2) s += s_red[t + p2 * O];
      atomicAdd(&stats[1024 + t], s);
    }
  }
}

// ---------------------------------------------------------------------------
// bn_apply (finalize inlined) + transpose; packed bf16 write for conv1d MFMA.
// ---------------------------------------------------------------------------
template <int O>
__global__ __launch_bounds__(256) void bn_apply_kernel(
    const float* __restrict__ ymax, const float* __restrict__ ymin,
    const float* __restrict__ stats, const float* __restrict__ g,
    const float* __restrict__ bb, float* __restrict__ hout,
    unsigned short* __restrict__ hp, int coff) {
  constexpr int OT = O / 32;
  __shared__ float s_t[32][33];
  const int t = threadIdx.x;
  const int bx = blockIdx.x;
  const int b = bx / (32 * OT);
  const int r = bx % (32 * OT);
  const int n0 = (r / OT) * 32;
  const int o0 = (r % OT) * 32;
  const int col = t & 31, rowb = t >> 5;
  const int o = o0 + col;
  const float inv = 1.f / (8.f * 1024.f * 20.f);
  const float mean = stats[o] * inv;
  const float var = stats[1024 + o] * inv - mean * mean;
  const float sc = g[o] * rsqrtf(var + BNEPS);
  const float sh = bb[o] - mean * sc;
  const float* src = (sc >= 0.f) ? ymax : ymin;
  const int c = coff + o;               // conv1d K index
#pragma unroll
  for (int rr = 0; rr < 4; ++rr) {
    const int nl = n0 + rowb + rr * 8;
    const float y = src[((size_t)(b << 10) + nl) * O + o];
    const float h = lrelu(fmaf(sc, y, sh));
    s_t[rowb + rr * 8][col] = h;
    if (hp) {
      const int lane2 = (nl & 31) + ((c >> 3) & 1) * 32;
      hp[(((size_t)(b * 32 + (nl >> 5)) * 32 + (c >> 4)) * 64 + lane2) * 8 +
         (c & 7)] = f2b(h);
    }
  }
  __syncthreads();
#pragma unroll
  for (int rr = 0; rr < 4; ++rr) {
    const int ol = rowb + rr * 8;
    hout[(size_t)b * (512 * 1024) + (o0 + ol) * NN + n0 + col] = s_t[col][ol];
  }
}

// ---------------------------------------------------------------------------
// conv1d via MFMA on packed fragments: Y5[b][o][n] = sum_c W5[o][c]*h[b][n][c]
// ---------------------------------------------------------------------------
__global__ __launch_bounds__(256) void conv1d_mfma_kernel(
    const unsigned short* __restrict__ hp,
    const unsigned short* __restrict__ w5p, float* __restrict__ Y5) {
  const int t = threadIdx.x, bx = blockIdx.x;
  const int b = bx >> 6;
  const int r = bx & 63;
  const int w = t >> 6, lane = t & 63;
  const int ot0 = (r >> 3) * 4 + (w & 1) * 2;
  const int nt0 = (r & 7) * 4 + (w >> 1) * 2;
  const unsigned short* a0p = w5p + (size_t)ot0 * 16384 + lane * 8;
  const unsigned short* a1p = a0p + 16384;
  const unsigned short* b0p = hp + (size_t)(b * 32 + nt0) * 16384 + lane * 8;
  const unsigned short* b1p = b0p + 16384;
  f32x16 acc00, acc01, acc10, acc11;
#pragma unroll
  for (int i = 0; i < 16; ++i) { acc00[i] = 0.f; acc01[i] = 0.f; acc10[i] = 0.f; acc11[i] = 0.f; }
#pragma unroll 2
  for (int kb = 0; kb < 32; ++kb) {
    const int off = kb * 512;
    const short8v a0 = *(const short8v*)(a0p + off);
    const short8v a1 = *(const short8v*)(a1p + off);
    const short8v b0 = *(const short8v*)(b0p + off);
    const short8v b1 = *(const short8v*)(b1p + off);
    acc00 = __builtin_amdgcn_mfma_f32_32x32x16_bf16(a0, b0, acc00, 0, 0, 0);
    acc01 = __builtin_amdgcn_mfma_f32_32x32x16_bf16(a0, b1, acc01, 0, 0, 0);
    acc10 = __builtin_amdgcn_mfma_f32_32x32x16_bf16(a1, b0, acc10, 0, 0, 0);
    acc11 = __builtin_amdgcn_mfma_f32_32x32x16_bf16(a1, b1, acc11, 0, 0, 0);
  }
  const int l31 = lane & 31, l5 = lane >> 5;
#pragma unroll
  for (int oi = 0; oi < 2; ++oi) {
#pragma unroll
    for (int nj = 0; nj < 2; ++nj) {
      const f32x16 a = (oi == 0) ? (nj == 0 ? acc00 : acc01)
                                 : (nj == 0 ? acc10 : acc11);
      const int ob = (ot0 + oi) * 32;
      const int nb = (nt0 + nj) * 32;
#pragma unroll
      for (int r16 = 0; r16 < 16; ++r16) {
        const int row = (r16 & 3) + 8 * (r16 >> 2) + 4 * l5;
        Y5[((size_t)(b << 10) + ob + row) * 1024 + nb + l31] = a[r16];
      }
    }
  }
}

// ---------------------------------------------------------------------------
// fused conv1d BN stats + finalize + pool: one block per channel o.
// ---------------------------------------------------------------------------
__global__ __launch_bounds__(256) void c1pool_kernel(
    const float* __restrict__ Y5, const float* __restrict__ g,
    const float* __restrict__ bb, float* __restrict__ z) {
  __shared__ float sr[256];
  __shared__ float s_par[2];
  const int o = blockIdx.x, t = threadIdx.x;
  float s1 = 0.f, s2 = 0.f;
#pragma unroll
  for (int b = 0; b < 8; ++b) {
    const float4 v = *(const float4*)&Y5[((size_t)((b << 10) + o)) * 1024 + t * 4];
    s1 += v.x + v.y + v.z + v.w;
    s2 = fmaf(v.x, v.x, s2);
    s2 = fmaf(v.y, v.y, s2);
    s2 = fmaf(v.z, v.z, s2);
    s2 = fmaf(v.w, v.w, s2);
  }
  sr[t] = s1;
  __syncthreads();
  for (int s = 128; s > 0; s >>= 1) {
    if (t < s) sr[t] += sr[t + s];
    __syncthreads();
  }
  if (t == 0) s_par[0] = sr[0];
  __syncthreads();
  sr[t] = s2;
  __syncthreads();
  for (int s = 128; s > 0; s >>= 1) {
    if (t < s) sr[t] += sr[t + s];
    __syncthreads();
  }
  if (t == 0) {
    const float mean = s_par[0] * (1.f / 8192.f);
    const float var = sr[0] * (1.f / 8192.f) - mean * mean;
    const float sc = g[o] * rsqrtf(var + BNEPS);
    s_par[0] = sc;
    s_par[1] = bb[o] - mean * sc;
  }
  __syncthreads();
  const float sc = s_par[0], sh = s_par[1];
  const int lane = t & 63, w = t >> 6;
#pragma unroll
  for (int h = 0; h < 2; ++h) {
    const int b = w + h * 4;
    const float* yr = Y5 + ((size_t)((b << 10) + o)) * 1024 + lane * 16;
    float mx = -3.4e38f, sm = 0.f;
#pragma unroll
    for (int j = 0; j < 4; ++j) {
      const float4 v = *(const float4*)&yr[j * 4];
      const float y0 = lrelu(fmaf(sc, v.x, sh));
      const float y1 = lrelu(fmaf(sc, v.y, sh));
      const float y2 = lrelu(fmaf(sc, v.z, sh));
      const float y3 = lrelu(fmaf(sc, v.w, sh));
      mx = fmaxf(fmaxf(fmaxf(mx, y0), fmaxf(y1, y2)), y3);
      sm += y0 + y1 + y2 + y3;
    }
#pragma unroll
    for (int off = 1; off < 64; off <<= 1) {
      mx = fmaxf(mx, __shfl_xor(mx, off, 64));
      sm += __shfl_xor(sm, off, 64);
    }
    if (lane == 0) {
      z[b * 2048 + o] = mx;
      z[b * 2048 + 1024 + o] = sm * (1.f / 1024.f);
    }
  }
}

// ---------------------------------------------------------------------------
// fallback f32 conv1d (used only if ws too small for MFMA buffers)
// ---------------------------------------------------------------------------
__global__ void bn_finalize_kernel(float* __restrict__ stats,
                                   const float* __restrict__ g,
                                   const float* __restrict__ bb, int cout,
                                   float inv_cnt) {
  const int o = blockIdx.x * 256 + threadIdx.x;
  if (o >= cout) return;
  const float mean = stats[o] * inv_cnt;
  const float var = stats[1024 + o] * inv_cnt - mean * mean;
  const float s = g[o] * rsqrtf(var + BNEPS);
  stats[2048 + o] = s;
  stats[3072 + o] = bb[o] - mean * s;
}

__global__ __launch_bounds__(256) void conv1d_gemm_kernel(
    const float* __restrict__ hcat, const float* __restrict__ WT5,
    float* __restrict__ stats, float* __restrict__ Y5) {
  __shared__ __align__(16) float s_w[8][64];
  __shared__ __align__(16) float s_h[8][64];
  __shared__ __align__(16) float s_red[64][16];
  const int t = threadIdx.x;
  const int bx = blockIdx.x;
  const int b = bx >> 8;
  const int o0 = ((bx >> 4) & 15) * 64;
  const int n0 = (bx & 15) * 64;
  const float* hb = hcat + (size_t)b * (512 * 1024);
  const int to = (t >> 4) * 4;
  const int tn = (t & 15) * 4;
  float acc[4][4] = {};
  for (int c0 = 0; c0 < 512; c0 += 8) {
    for (int i = t; i < 8 * 64; i += 256) {
      const int cc = i >> 6, col = i & 63;
      s_w[cc][col] = WT5[(c0 + cc) * 1024 + o0 + col];
      s_h[cc][col] = hb[(c0 + cc) * NN + n0 + col];
    }
    __syncthreads();
#pragma unroll
    for (int cc = 0; cc < 8; ++cc) {
      const float4 wv = *(const float4*)&s_w[cc][to];
      const float4 hv = *(const float4*)&s_h[cc][tn];
      const float wa[4] = {wv.x, wv.y, wv.z, wv.w};
      const float ha[4] = {hv.x, hv.y, hv.z, hv.w};
#pragma unroll
      for (int i = 0; i < 4; ++i)
#pragma unroll
        for (int j = 0; j < 4; ++j) acc[i][j] = fmaf(wa[i], ha[j], acc[i][j]);
    }
    __syncthreads();
  }
#pragma unroll
  for (int i = 0; i < 4; ++i) {
    *(float4*)&Y5[((size_t)(b << 10) + o0 + to + i) * NN + n0 + tn] =
        make_float4(acc[i][0], acc[i][1], acc[i][2], acc[i][3]);
  }
#pragma unroll
  for (int i = 0; i < 4; ++i)
    s_red[to + i][t & 15] = acc[i][0] + acc[i][1] + acc[i][2] + acc[i][3];
  __syncthreads();
  if (t < 64) {
    float s = 0.f;
#pragma unroll
    for (int g2 = 0; g2 < 16; ++g2) s += s_red[t][g2];
    atomicAdd(&stats[o0 + t], s);
  }
  __syncthreads();
#pragma unroll
  for (int i = 0; i < 4; ++i) {
    float s = 0.f;
#pragma unroll
    for (int j = 0; j < 4; ++j) s = fmaf(acc[i][j], acc[i][j], s);
    s_red[to + i][t & 15] = s;
  }
  __syncthreads();
  if (t < 64) {
    float s = 0.f;
#pragma unroll
    for (int g2 = 0; g2 < 16; ++g2) s += s_red[t][g2];
    atomicAdd(&stats[1024 + o0 + t], s);
  }
}

__global__ __launch_bounds__(256) void pool_kernel(
    const float* __restrict__ Y5, const float* __restrict__ stats,
    float* __restrict__ z) {
  const int t = threadIdx.x;
  const int lane = t & 63;
  const int bx = blockIdx.x;
  const int b = bx >> 8;
  const int o = (bx & 255) * 4 + (t >> 6);
  const float sc = stats[2048 + o], sh = stats[3072 + o];
  const float* yr = Y5 + ((size_t)(b << 10) + o) * NN;
  float mx = -3.4e38f, sm = 0.f;
#pragma unroll
  for (int j = 0; j < 16; ++j) {
    const float y = lrelu(fmaf(sc, yr[j * 64 + lane], sh));
    mx = fmaxf(mx, y);
    sm += y;
  }
  for (int off = 32; off > 0; off >>= 1) {
    mx = fmaxf(mx, __shfl_down(mx, off, 64));
    sm += __shfl_down(sm, off, 64);
  }
  if (lane == 0) {
    z[b * 2048 + o] = mx;
    z[b * 2048 + 1024 + o] = sm * (1.f / 1024.f);
  }
}

// ---------------------------------------------------------------------------
// MLP layer with batch-of-8 BN + lrelu fused.
// ---------------------------------------------------------------------------
__global__ __launch_bounds__(256) void mlp_kernel(
    const float* __restrict__ zin, const float* __restrict__ W,
    const float* __restrict__ bias, const float* __restrict__ g,
    const float* __restrict__ bb, int kin, float* __restrict__ out, int O) {
  __shared__ float s_red[256];
  __shared__ float s_y[8];
  const int t = threadIdx.x;
  const int o = blockIdx.x;
  float acc[8];
#pragma unroll
  for (int b = 0; b < 8; ++b) acc[b] = 0.f;
  for (int c = t; c < kin; c += 256) {
    const float w = W[(size_t)o * kin + c];
#pragma unroll
    for (int b = 0; b < 8; ++b) acc[b] = fmaf(w, zin[b * kin + c], acc[b]);
  }
  for (int b = 0; b < 8; ++b) {
    s_red[t] = acc[b];
    __syncthreads();
    for (int s = 128; s > 0; s >>= 1) {
      if (t < s) s_red[t] += s_red[t + s];
      __syncthreads();
    }
    if (t == 0) s_y[b] = s_red[0] + (bias ? bias[o] : 0.f);
    __syncthreads();
  }
  if (t == 0) {
    float m = 0.f;
    for (int b = 0; b < 8; ++b) m += s_y[b];
    m *= 0.125f;
    float v = 0.f;
    for (int b = 0; b < 8; ++b) { const float d = s_y[b] - m; v = fmaf(d, d, v); }
    v *= 0.125f;
    const float s = g[o] * rsqrtf(v + BNEPS);
    const float sh = bb[o] - m * s;
    for (int b = 0; b < 8; ++b) out[b * O + o] = lrelu(fmaf(s, s_y[b], sh));
  }
}

// final: out = z2 @ Wl3^T + bl3; output dtype derived from flags here.
__global__ void final_kernel(const float* __restrict__ z2,
                             const float* __restrict__ Wl3,
                             const float* __restrict__ bl3,
                             const int* __restrict__ flags, void* out) {
  const int j = blockIdx.x * 256 + threadIdx.x;
  if (j >= 320) return;
  int anyf32 = 0, anybf = 0;
  for (int i = 0; i < NIN; ++i) {
    const int fl = flags[i];
    if (fl == 0) anyf32 = 1;
    if (fl == 1) anybf = 1;
  }
  const int bf16out = (anybf && !anyf32) ? 1 : 0;
  const int b = j / 40, o = j - b * 40;
  float s = bl3[o];
  for (int c = 0; c < 256; ++c) s = fmaf(z2[b * 256 + c], Wl3[o * 256 + c], s);
  if (bf16out) ((__hip_bfloat16*)out)[j] = __float2bfloat16(s);
  else ((float*)out)[j] = s;
}

// ---------------------------------------------------------------------------
template <int C, int O>
static void run_stage(float* wsf, const float* xbase, int bstr, int widx,
                      int gidx, int bidx, int stat, float* hout,
                      unsigned short* hp, int coff, hipStream_t stream) {
  int* idxb = reinterpret_cast<int*>(wsf + IDXo);
  float* dist = wsf + DISTo;
  float* U = wsf + U_OFF;
  float* Vd = wsf + VD_OFF;
  float* ymx = wsf + YMX_OFF;
  float* ymn = wsf + YMN_OFF;
  float* stats = wsf + STATSo + stat * 4096;
  dist2_kernel<C><<<BB * 36, 256, 0, stream>>>(xbase, bstr, dist);
  tg_kernel<C, O><<<2048 + BB * 16 * (O / 64), 256, 0, stream>>>(
      dist, idxb, xbase, bstr, wsf + widx, U, Vd);
  edge_pass_kernel<O><<<1024, 256, 0, stream>>>(U, Vd, idxb, stats, ymx, ymn);
  bn_apply_kernel<O><<<BB * 32 * (O / 32), 256, 0, stream>>>(
      ymx, ymn, stats, wsf + gidx, wsf + bidx, hout, hp, coff);
}

extern "C" void kernel_launch(void* const* d_in, const int* in_sizes, int n_in,
                              void* d_out, int out_size, void* d_ws,
                              size_t ws_size, hipStream_t stream) {
  (void)in_sizes; (void)n_in; (void)out_size;
  float* wsf = reinterpret_cast<float*>(d_ws);
  int* flags = reinterpret_cast<int*>(wsf + FLAGSo);
  float* hcat = wsf + HCATo;
  const bool mf = ws_size >= WS_NEED_MFMA;
  unsigned short* hp = mf ? reinterpret_cast<unsigned short*>(wsf + HBFo) : nullptr;
  unsigned short* w5p = reinterpret_cast<unsigned short*>(wsf + W5BFo);

  Ptrs ptrs;
  for (int i = 0; i < NIN; ++i) ptrs.p[i] = d_in[i];

  detect_kernel<<<NIN, 64, 0, stream>>>(ptrs, flags);
  convert_kernel<<<NCONV + 80 + 256, 256, 0, stream>>>(ptrs, flags, wsf,
                                                       mf ? 1 : 0);

  run_stage<3, 64>(wsf, wsf + XIN, 3 * NN, WT1, G1, B1o, 0, hcat, hp, 0,
                   stream);
  run_stage<64, 64>(wsf, hcat, 512 * NN, WT2, G2, B2o, 1, hcat + 64 * NN, hp,
                    64, stream);
  run_stage<64, 128>(wsf, hcat + 64 * NN, 512 * NN, WT3, G3, B3o, 2,
                     hcat + 128 * NN, hp, 128, stream);
  run_stage<128, 256>(wsf, hcat + 128 * NN, 512 * NN, WT4, G4, B4o, 3,
                      hcat + 256 * NN, hp, 256, stream);

  // conv1d 512->1024 + BN + pool
  float* Y5 = wsf + Y5_OFF;
  float* st5 = wsf + STATSo + 4 * 4096;
  if (mf) {
    conv1d_mfma_kernel<<<512, 256, 0, stream>>>(hp, w5p, Y5);
    c1pool_kernel<<<1024, 256, 0, stream>>>(Y5, wsf + G5, wsf + B5o,
                                            wsf + Z2048o);
  } else {
    conv1d_gemm_kernel<<<2048, 256, 0, stream>>>(hcat, wsf + WT5, st5, Y5);
    bn_finalize_kernel<<<4, 256, 0, stream>>>(st5, wsf + G5, wsf + B5o, 1024,
                                              1.f / 8192.f);
    pool_kernel<<<BB * 256, 256, 0, stream>>>(Y5, st5, wsf + Z2048o);
  }

  // MLP head
  mlp_kernel<<<512, 256, 0, stream>>>(wsf + Z2048o, wsf + WL1, nullptr,
      wsf + G6, wsf + B6o, 2048, wsf + Z1o, 512);
  mlp_kernel<<<256, 256, 0, stream>>>(wsf + Z1o, wsf + WL2, wsf + BL2o,
      wsf + G7, wsf + B7o, 512, wsf + Z2o, 256);
  final_kernel<<<2, 256, 0, stream>>>(wsf + Z2o, wsf + WL3, wsf + BL3o,
      flags, d_out);
}

// Round 13
// 494.283 us; speedup vs baseline: 1.3301x; 1.1096x over previous
//
#include <hip/hip_runtime.h>
#include <hip/hip_bf16.h>
#include <cstdint>

// ---------------------------------------------------------------------------
// DGCNN forward on MI355X. Math f32; conv1d via bf16 MFMA on packed
// fragment layouts; kNN via dist GEMM (fused xx) + register-queue wave top-k.
// R13: exact restoration of the R10 configuration (measured 505 us):
// full 64-tile dist2 (symmetric-mirror variant regressed: scattered
// transposed stores), edge_pass v1 @ grid 512 (scalar gather = max MLP),
// merged topk+gemm_uv, conv1d MFMA, fused c1pool, convert with tails.
// ---------------------------------------------------------------------------

static constexpr int BB  = 8;
static constexpr int NN  = 1024;
static constexpr int KNB = 20;
static constexpr float BNEPS = 1e-5f;

static constexpr int NIN = 25;

__constant__ int c_cum[NIN + 1] = {
    0, 24576, 24960, 33152, 49536, 115072, 639360,
    1687936, 1819008, 1819264, 1829504, 1829544, 1829608, 1829672, 1829736,
    1829800, 1829928, 1830056, 1830312, 1830568, 1831592, 1832616, 1833128,
    1833640, 1833896, 1834152};
__constant__ int c_trO[NIN] = {0, 64, 64, 128, 256, 1024, 0, 0, 0, 0, 0,
                               0, 0, 0, 0, 0, 0, 0, 0, 0, 0, 0, 0, 0, 0};
__constant__ int c_trI[NIN] = {0, 6, 128, 128, 256, 512, 0, 0, 0, 0, 0,
                               0, 0, 0, 0, 0, 0, 0, 0, 0, 0, 0, 0, 0, 0};

enum : int {
  XIN = 0, WT1 = 24576, WT2 = 24960, WT3 = 33152, WT4 = 49536, WT5 = 115072,
  WL1 = 639360, WL2 = 1687936, BL2o = 1819008, WL3 = 1819264, BL3o = 1829504,
  G1 = 1829544, B1o = 1829608, G2 = 1829672, B2o = 1829736,
  G3 = 1829800, B3o = 1829928, G4 = 1830056, B4o = 1830312,
  G5 = 1830568, B5o = 1831592, G6 = 1832616, B6o = 1833128,
  G7 = 1833640, B7o = 1833896,
  IDXo = 1842432,       // 163840 i32
  HCATo = 2006272,      // 8*512*1024 f
  STATSo = 6200576,     // 5 layers * 4096 f
  Z2048o = 6237440,     // 8*2048 f
  Z1o = 6253824,        // 8*512 f
  Z2o = 6257920,        // 8*256 f
  FLAGSo = 6259968,     // 32 i32
  DISTo = 6260736,      // 8M-float window (sequentially reused)
  HBFo  = 14649344,     // packed bf16 h: 8*1024*512 shorts (2M float slots)
  W5BFo = 16746496      // packed bf16 w5: 512K shorts -> ends 17008640
};
static constexpr int TOTAL_IN = 1834152;
static constexpr int NCONV = (TOTAL_IN + 255) / 256;   // 7165 blocks
// window reuse: dist [0,8M) -> dead after topk;
// U [0,2M), Vd [2M,4M), ymax [4M,6M), ymin [6M,8M); Y5 reuses [0,2M).
static constexpr int U_OFF   = DISTo + 0;
static constexpr int VD_OFF  = DISTo + 2097152;
static constexpr int YMX_OFF = DISTo + 4194304;
static constexpr int YMN_OFF = DISTo + 6291456;
static constexpr int Y5_OFF  = DISTo + 0;
static constexpr size_t WS_NEED_MFMA = (size_t)17008640 * 4;  // ~68 MB

struct Ptrs { const void* p[NIN]; };

typedef short short8v __attribute__((ext_vector_type(8)));
typedef float f32x16 __attribute__((ext_vector_type(16)));

__device__ __forceinline__ float lrelu(float y) { return (y < 0.f) ? 0.2f * y : y; }
__device__ __forceinline__ unsigned short f2b(float f) {
  unsigned u = __float_as_uint(f);
  unsigned r = (u + 0x7FFFu + ((u >> 16) & 1u)) >> 16;   // RNE
  return (unsigned short)r;
}
// composite key: larger value wins; tie -> lower global index (jax top_k)
__device__ __forceinline__ bool kbetter(float v, int i, float v2, int i2) {
  return v > v2 || (v == v2 && i < i2);
}
__device__ __forceinline__ float load_in(const void* p, int fl, int idx) {
  if (fl == 2) return 0.f;
  if (fl == 1) {
    const unsigned short u = ((const unsigned short*)p)[idx];
    return __uint_as_float(((unsigned)u) << 16);
  }
  return ((const float*)p)[idx];
}

// ---------------------------------------------------------------------------
// dtype detection
// ---------------------------------------------------------------------------
__global__ void detect_kernel(Ptrs ptrs, int* __restrict__ flags) {
  const int i = blockIdx.x;
  const unsigned* p = (const unsigned*)ptrs.p[i];
  const int n = c_cum[i + 1] - c_cum[i];
  int words = n >> 1; if (words > 64) words = 64;
  const int t = threadIdx.x;
  unsigned w = (t < words) ? p[t] : 0u;
  bool nz = (w != 0u);
  unsigned e = (w >> 7) & 0xFFu;
  bool pl = nz && (e >= 96u) && (e <= 140u);
  unsigned long long mnz = __ballot(nz);
  unsigned long long mpl = __ballot(pl);
  if (t == 0) {
    int cnz = __popcll(mnz), cpl = __popcll(mpl);
    flags[i] = (cnz == 0) ? 2 : ((2 * cpl > words) ? 1 : 0);
  }
}

// ---------------------------------------------------------------------------
// convert: main blocks convert+transpose inputs; tail1 zeroes stats;
// tail2 packs w5 (raw input -> MFMA A-fragment bf16) if do_w5.
// ---------------------------------------------------------------------------
__global__ void convert_kernel(Ptrs ptrs, const int* __restrict__ flags,
                               float* __restrict__ ws, int do_w5) {
  const int bx = blockIdx.x;
  const int t = threadIdx.x;
  if (bx >= NCONV + 80) {            // tail2: w5 packing
    if (!do_w5) return;
    const int g = (bx - NCONV - 80) * 256 + t;   // 0..65535
    const int lane = g & 63;
    const int kb = (g >> 6) & 31;
    const int ot = g >> 11;
    const int o = ot * 32 + (lane & 31);
    const int k0 = kb * 16 + (lane >> 5) * 8;
    const void* w5raw = ptrs.p[5];
    const int fl = flags[5];
    unsigned u[4];
#pragma unroll
    for (int h = 0; h < 4; ++h) {
      const unsigned short lo = f2b(load_in(w5raw, fl, o * 512 + k0 + 2 * h));
      const unsigned short hi = f2b(load_in(w5raw, fl, o * 512 + k0 + 2 * h + 1));
      u[h] = (unsigned)lo | ((unsigned)hi << 16);
    }
    unsigned short* w5p = (unsigned short*)(ws + W5BFo);
    *(uint4*)&w5p[(size_t)g * 8] = make_uint4(u[0], u[1], u[2], u[3]);
    return;
  }
  if (bx >= NCONV) {                 // tail1: zero stats
    const int z = (bx - NCONV) * 256 + t;
    if (z < 20480) ws[STATSo + z] = 0.f;
    return;
  }
  const int e = bx * 256 + t;
  if (e >= TOTAL_IN) return;
  int i = 0;
  while (e >= c_cum[i + 1]) ++i;
  const int el = e - c_cum[i];
  int src;
  const int O = c_trO[i];
  if (O > 0) {
    const int I = c_trI[i];
    const int o = el % O, ii = el / O;
    src = o * I + ii;
  } else src = el;
  ws[e] = load_in(ptrs.p[i], flags[i], src);
}

// ---------------------------------------------------------------------------
// dist GEMM 8x8 reg tile, xx fused: D[b][n][m] = 2*dot - xx[n] - xx[m]
// 128x128 block tile, grid 512 (8b x 8 x 8). Full 64 tiles per batch.
// ---------------------------------------------------------------------------
template <int C>
__global__ __launch_bounds__(256) void dist2_kernel(
    const float* __restrict__ xbase, int bstr, float* __restrict__ D) {
  __shared__ __align__(16) float s_a[16][128];
  __shared__ __align__(16) float s_b[16][128];
  __shared__ float s_xx[256];   // [0,128): row norms; [128,256): col norms
  const int t = threadIdx.x;
  const int bx = blockIdx.x;
  const int b = bx >> 6;
  const int r = bx & 63;
  const int tn0 = (r >> 3) * 128;
  const int tm0 = (r & 7) * 128;
  const float* xb = xbase + (size_t)b * bstr;
  {
    const int idx = (t < 128) ? (tn0 + t) : (tm0 + (t - 128));
    float s = 0.f;
    for (int c = 0; c < C; ++c) {
      const float v = xb[c * NN + idx];
      s = fmaf(v, v, s);
    }
    s_xx[t] = s;
  }
  const int tn = (t >> 4) * 8;
  const int tm = (t & 15) * 8;
  float acc[8][8] = {};
  for (int c0 = 0; c0 < C; c0 += 16) {
    const int kc = (C - c0 < 16) ? (C - c0) : 16;
    __syncthreads();
    for (int i = t; i < 512; i += 256) {
      const int cc = i >> 5, col4 = (i & 31) * 4;
      float4 va = make_float4(0.f, 0.f, 0.f, 0.f), vb = va;
      if (cc < kc) {
        va = *(const float4*)&xb[(c0 + cc) * NN + tn0 + col4];
        vb = *(const float4*)&xb[(c0 + cc) * NN + tm0 + col4];
      }
      *(float4*)&s_a[cc][col4] = va;
      *(float4*)&s_b[cc][col4] = vb;
    }
    __syncthreads();
#pragma unroll
    for (int cc = 0; cc < 16; ++cc) {
      const float4 a0 = *(const float4*)&s_a[cc][tn];
      const float4 a1 = *(const float4*)&s_a[cc][tn + 4];
      const float4 b0 = *(const float4*)&s_b[cc][tm];
      const float4 b1 = *(const float4*)&s_b[cc][tm + 4];
      const float aa[8] = {a0.x, a0.y, a0.z, a0.w, a1.x, a1.y, a1.z, a1.w};
      const float bb2[8] = {b0.x, b0.y, b0.z, b0.w, b1.x, b1.y, b1.z, b1.w};
#pragma unroll
      for (int i = 0; i < 8; ++i)
#pragma unroll
        for (int j = 0; j < 8; ++j) acc[i][j] = fmaf(aa[i], bb2[j], acc[i][j]);
    }
  }
  float xmv[8];
#pragma unroll
  for (int j = 0; j < 8; ++j) xmv[j] = s_xx[128 + tm + j];
  float* Db = D + ((size_t)b << 20);
#pragma unroll
  for (int i = 0; i < 8; ++i) {
    const float xxn = s_xx[tn + i];
    float4 o0v, o1v;
    o0v.x = 2.f * acc[i][0] - xxn - xmv[0];
    o0v.y = 2.f * acc[i][1] - xxn - xmv[1];
    o0v.z = 2.f * acc[i][2] - xxn - xmv[2];
    o0v.w = 2.f * acc[i][3] - xxn - xmv[3];
    o1v.x = 2.f * acc[i][4] - xxn - xmv[4];
    o1v.y = 2.f * acc[i][5] - xxn - xmv[5];
    o1v.z = 2.f * acc[i][6] - xxn - xmv[6];
    o1v.w = 2.f * acc[i][7] - xxn - xmv[7];
    float* row = &Db[(size_t)(tn0 + tn + i) * NN + tm0 + tm];
    *(float4*)row = o0v;
    *(float4*)(row + 4) = o1v;
  }
}

// ---------------------------------------------------------------------------
// topk helpers (per-lane sorted top-4 queue, disjoint ascending col ranges)
// ---------------------------------------------------------------------------
__device__ __forceinline__ void tk_ins(float v, int i, float lv[4], int li[4]) {
  if (kbetter(v, i, lv[3], li[3])) {
    lv[3] = v; li[3] = i;
    if (kbetter(lv[3], li[3], lv[2], li[2])) {
      float tv = lv[2]; int ti = li[2];
      lv[2] = lv[3]; li[2] = li[3]; lv[3] = tv; li[3] = ti;
    }
    if (kbetter(lv[2], li[2], lv[1], li[1])) {
      float tv = lv[1]; int ti = li[1];
      lv[1] = lv[2]; li[1] = li[2]; lv[2] = tv; li[2] = ti;
    }
    if (kbetter(lv[1], li[1], lv[0], li[0])) {
      float tv = lv[0]; int ti = li[0];
      lv[0] = lv[1]; li[0] = li[1]; lv[1] = tv; li[1] = ti;
    }
  }
}

__device__ __forceinline__ void tk_build(const float* __restrict__ Dr, int base,
                                         unsigned mask, float lv[4], int li[4]) {
#pragma unroll
  for (int q = 0; q < 4; ++q) { lv[q] = -3.4e38f; li[q] = 0x7FFFFFFF; }
  const float4 a0 = *(const float4*)&Dr[base + 0];
  const float4 a1 = *(const float4*)&Dr[base + 4];
  const float4 a2 = *(const float4*)&Dr[base + 8];
  const float4 a3 = *(const float4*)&Dr[base + 12];
  const float vs[16] = {a0.x, a0.y, a0.z, a0.w, a1.x, a1.y, a1.z, a1.w,
                        a2.x, a2.y, a2.z, a2.w, a3.x, a3.y, a3.z, a3.w};
#pragma unroll
  for (int j = 0; j < 16; ++j)
    if (!((mask >> j) & 1u)) tk_ins(vs[j], base + j, lv, li);
}

// ---------------------------------------------------------------------------
// merged topk (blocks 0..2047) + gemm_uv (blocks 2048..): independent work,
// one launch. topk v5: value-only butterfly + ballot/ffs winner (lanes own
// disjoint ascending index ranges -> lowest set lane == lowest tied index).
// ---------------------------------------------------------------------------
template <int C, int O>
__global__ __launch_bounds__(256) void tg_kernel(
    const float* __restrict__ D, int* __restrict__ idxb,
    const float* __restrict__ xbase, int bstr, const float* __restrict__ WT,
    float* __restrict__ U, float* __restrict__ Vd) {
  constexpr int OT = O / 64;
  const int t = threadIdx.x;
  if (blockIdx.x < 2048) {
    const int lane = t & 63;
    const int row = blockIdx.x * 4 + (t >> 6);
    const float* Dr = D + ((size_t)row << 10);
    const int base = lane * 16;
    float lv[4]; int li[4];
    unsigned mask = 0;
    tk_build(Dr, base, 0u, lv, li);
    for (int kk = 0; kk < KNB; ++kk) {
      float bv = lv[0];
#pragma unroll
      for (int off = 1; off < 64; off <<= 1)
        bv = fmaxf(bv, __shfl_xor(bv, off, 64));
      const unsigned long long m = __ballot(lv[0] == bv);
      const int wl = __ffsll(m) - 1;
      const int bi = __shfl(li[0], wl, 64);
      if (lane == 0) idxb[row * KNB + kk] = bi;
      if (lane == wl) {
        mask |= 1u << (bi & 15);
        lv[0] = lv[1]; li[0] = li[1];
        lv[1] = lv[2]; li[1] = li[2];
        lv[2] = lv[3]; li[2] = li[3];
        lv[3] = -3.4e38f; li[3] = 0x7FFFFFFF;
        if (li[0] == 0x7FFFFFFF && __popc(mask) < 16)
          tk_build(Dr, base, mask, lv, li);   // rare rescan
      }
    }
    return;
  }
  // ---- gemm_uv part ----
  __shared__ __align__(16) float s_x[8][64];
  __shared__ __align__(16) float s_wn[8][64];
  __shared__ __align__(16) float s_wc[8][64];
  const int bx = blockIdx.x - 2048;
  const int b = bx / (16 * OT);
  const int r = bx % (16 * OT);
  const int n0 = (r / OT) * 64;
  const int o0 = (r % OT) * 64;
  const float* xb = xbase + (size_t)b * bstr;
  const int tn = (t >> 4) * 4;
  const int to = (t & 15) * 4;
  float accU[4][4] = {}, accC[4][4] = {};
  for (int c0 = 0; c0 < C; c0 += 8) {
    const int kc = (C - c0 < 8) ? (C - c0) : 8;
    for (int i = t; i < 8 * 64; i += 256) {
      const int cc = i >> 6, col = i & 63;
      const bool ok = cc < kc;
      s_x[cc][col]  = ok ? xb[(c0 + cc) * NN + n0 + col] : 0.f;
      s_wn[cc][col] = ok ? WT[(c0 + cc) * O + o0 + col] : 0.f;
      s_wc[cc][col] = ok ? WT[(C + c0 + cc) * O + o0 + col] : 0.f;
    }
    __syncthreads();
#pragma unroll
    for (int cc = 0; cc < 8; ++cc) {
      const float4 xv = *(const float4*)&s_x[cc][tn];
      const float4 wn = *(const float4*)&s_wn[cc][to];
      const float4 wc = *(const float4*)&s_wc[cc][to];
      const float xa[4] = {xv.x, xv.y, xv.z, xv.w};
      const float na[4] = {wn.x, wn.y, wn.z, wn.w};
      const float ca[4] = {wc.x, wc.y, wc.z, wc.w};
#pragma unroll
      for (int i = 0; i < 4; ++i)
#pragma unroll
        for (int j = 0; j < 4; ++j) {
          accU[i][j] = fmaf(xa[i], na[j], accU[i][j]);
          accC[i][j] = fmaf(xa[i], ca[j], accC[i][j]);
        }
    }
    __syncthreads();
  }
#pragma unroll
  for (int i = 0; i < 4; ++i) {
    const size_t base2 = ((size_t)(b << 10) + n0 + tn + i) * O + o0 + to;
    *(float4*)&U[base2] = make_float4(accU[i][0], accU[i][1], accU[i][2], accU[i][3]);
    *(float4*)&Vd[base2] = make_float4(accC[i][0] - accU[i][0], accC[i][1] - accU[i][1],
                                       accC[i][2] - accU[i][2], accC[i][3] - accU[i][3]);
  }
}

// ---------------------------------------------------------------------------
// edge gather pass (v1): scalar per-o loads = max outstanding misses.
// y_k = U[b,idx_k,o] + Vd[b,n,o]; ymax/ymin + BN sums.
// ---------------------------------------------------------------------------
template <int O>
__global__ __launch_bounds__(256) void edge_pass_kernel(
    const float* __restrict__ U, const float* __restrict__ Vd,
    const int* __restrict__ idxb, float* __restrict__ stats,
    float* __restrict__ ymax, float* __restrict__ ymin) {
  constexpr int PSUB = 256 / O;
  __shared__ float s_red[256];
  const int t = threadIdx.x;
  const int o = t & (O - 1);
  const int psub = t / O;
  float ls1 = 0.f, ls2 = 0.f;
  for (int p = blockIdx.x * PSUB + psub; p < BB * NN; p += gridDim.x * PSUB) {
    const int b = p >> 10;
    const float* ub = U + ((size_t)(b << 10)) * O;
    int id[KNB];
#pragma unroll
    for (int k = 0; k < KNB; ++k) id[k] = idxb[p * KNB + k];
    const float vd = Vd[(size_t)p * O + o];
    float ymx = -3.4e38f, ymn = 3.4e38f;
#pragma unroll
    for (int k = 0; k < KNB; ++k) {
      const float y = ub[(size_t)id[k] * O + o] + vd;
      ymx = fmaxf(ymx, y);
      ymn = fminf(ymn, y);
      ls1 += y;
      ls2 = fmaf(y, y, ls2);
    }
    ymax[(size_t)p * O + o] = ymx;
    ymin[(size_t)p * O + o] = ymn;
  }
  if (PSUB == 1) {
    atomicAdd(&stats[o], ls1);
    atomicAdd(&stats[1024 + o], ls2);
  } else {
    s_red[t] = ls1;
    __syncthreads();
    if (t < O) {
      float s = s_red[t];
#pragma unroll
      for (int p2 = 1; p2 < PSUB; ++p2) s += s_red[t + p2 * O];
      atomicAdd(&stats[t], s);
    }
    __syncthreads();
    s_red[t] = ls2;
    __syncthreads();
    if (t < O) {
      float s = s_red[t];
#pragma unroll
      for (int p2 = 1; p2 < PSUB; ++p2) s += s_red[t + p2 * O];
      atomicAdd(&stats[1024 + t], s);
    }
  }
}

// ---------------------------------------------------------------------------
// bn_apply (finalize inlined) + transpose; packed bf16 write for conv1d MFMA.
// ---------------------------------------------------------------------------
template <int O>
__global__ __launch_bounds__(256) void bn_apply_kernel(
    const float* __restrict__ ymax, const float* __restrict__ ymin,
    const float* __restrict__ stats, const float* __restrict__ g,
    const float* __restrict__ bb, float* __restrict__ hout,
    unsigned short* __restrict__ hp, int coff) {
  constexpr int OT = O / 32;
  __shared__ float s_t[32][33];
  const int t = threadIdx.x;
  const int bx = blockIdx.x;
  const int b = bx / (32 * OT);
  const int r = bx % (32 * OT);
  const int n0 = (r / OT) * 32;
  const int o0 = (r % OT) * 32;
  const int col = t & 31, rowb = t >> 5;
  const int o = o0 + col;
  const float inv = 1.f / (8.f * 1024.f * 20.f);
  const float mean = stats[o] * inv;
  const float var = stats[1024 + o] * inv - mean * mean;
  const float sc = g[o] * rsqrtf(var + BNEPS);
  const float sh = bb[o] - mean * sc;
  const float* src = (sc >= 0.f) ? ymax : ymin;
  const int c = coff + o;               // conv1d K index
#pragma unroll
  for (int rr = 0; rr < 4; ++rr) {
    const int nl = n0 + rowb + rr * 8;
    const float y = src[((size_t)(b << 10) + nl) * O + o];
    const float h = lrelu(fmaf(sc, y, sh));
    s_t[rowb + rr * 8][col] = h;
    if (hp) {
      const int lane2 = (nl & 31) + ((c >> 3) & 1) * 32;
      hp[(((size_t)(b * 32 + (nl >> 5)) * 32 + (c >> 4)) * 64 + lane2) * 8 +
         (c & 7)] = f2b(h);
    }
  }
  __syncthreads();
#pragma unroll
  for (int rr = 0; rr < 4; ++rr) {
    const int ol = rowb + rr * 8;
    hout[(size_t)b * (512 * 1024) + (o0 + ol) * NN + n0 + col] = s_t[col][ol];
  }
}

// ---------------------------------------------------------------------------
// conv1d via MFMA on packed fragments: Y5[b][o][n] = sum_c W5[o][c]*h[b][n][c]
// ---------------------------------------------------------------------------
__global__ __launch_bounds__(256) void conv1d_mfma_kernel(
    const unsigned short* __restrict__ hp,
    const unsigned short* __restrict__ w5p, float* __restrict__ Y5) {
  const int t = threadIdx.x, bx = blockIdx.x;
  const int b = bx >> 6;
  const int r = bx & 63;
  const int w = t >> 6, lane = t & 63;
  const int ot0 = (r >> 3) * 4 + (w & 1) * 2;
  const int nt0 = (r & 7) * 4 + (w >> 1) * 2;
  const unsigned short* a0p = w5p + (size_t)ot0 * 16384 + lane * 8;
  const unsigned short* a1p = a0p + 16384;
  const unsigned short* b0p = hp + (size_t)(b * 32 + nt0) * 16384 + lane * 8;
  const unsigned short* b1p = b0p + 16384;
  f32x16 acc00, acc01, acc10, acc11;
#pragma unroll
  for (int i = 0; i < 16; ++i) { acc00[i] = 0.f; acc01[i] = 0.f; acc10[i] = 0.f; acc11[i] = 0.f; }
#pragma unroll 2
  for (int kb = 0; kb < 32; ++kb) {
    const int off = kb * 512;
    const short8v a0 = *(const short8v*)(a0p + off);
    const short8v a1 = *(const short8v*)(a1p + off);
    const short8v b0 = *(const short8v*)(b0p + off);
    const short8v b1 = *(const short8v*)(b1p + off);
    acc00 = __builtin_amdgcn_mfma_f32_32x32x16_bf16(a0, b0, acc00, 0, 0, 0);
    acc01 = __builtin_amdgcn_mfma_f32_32x32x16_bf16(a0, b1, acc01, 0, 0, 0);
    acc10 = __builtin_amdgcn_mfma_f32_32x32x16_bf16(a1, b0, acc10, 0, 0, 0);
    acc11 = __builtin_amdgcn_mfma_f32_32x32x16_bf16(a1, b1, acc11, 0, 0, 0);
  }
  const int l31 = lane & 31, l5 = lane >> 5;
#pragma unroll
  for (int oi = 0; oi < 2; ++oi) {
#pragma unroll
    for (int nj = 0; nj < 2; ++nj) {
      const f32x16 a = (oi == 0) ? (nj == 0 ? acc00 : acc01)
                                 : (nj == 0 ? acc10 : acc11);
      const int ob = (ot0 + oi) * 32;
      const int nb = (nt0 + nj) * 32;
#pragma unroll
      for (int r16 = 0; r16 < 16; ++r16) {
        const int row = (r16 & 3) + 8 * (r16 >> 2) + 4 * l5;
        Y5[((size_t)(b << 10) + ob + row) * 1024 + nb + l31] = a[r16];
      }
    }
  }
}

// ---------------------------------------------------------------------------
// fused conv1d BN stats + finalize + pool: one block per channel o.
// ---------------------------------------------------------------------------
__global__ __launch_bounds__(256) void c1pool_kernel(
    const float* __restrict__ Y5, const float* __restrict__ g,
    const float* __restrict__ bb, float* __restrict__ z) {
  __shared__ float sr[256];
  __shared__ float s_par[2];
  const int o = blockIdx.x, t = threadIdx.x;
  float s1 = 0.f, s2 = 0.f;
#pragma unroll
  for (int b = 0; b < 8; ++b) {
    const float4 v = *(const float4*)&Y5[((size_t)((b << 10) + o)) * 1024 + t * 4];
    s1 += v.x + v.y + v.z + v.w;
    s2 = fmaf(v.x, v.x, s2);
    s2 = fmaf(v.y, v.y, s2);
    s2 = fmaf(v.z, v.z, s2);
    s2 = fmaf(v.w, v.w, s2);
  }
  sr[t] = s1;
  __syncthreads();
  for (int s = 128; s > 0; s >>= 1) {
    if (t < s) sr[t] += sr[t + s];
    __syncthreads();
  }
  if (t == 0) s_par[0] = sr[0];
  __syncthreads();
  sr[t] = s2;
  __syncthreads();
  for (int s = 128; s > 0; s >>= 1) {
    if (t < s) sr[t] += sr[t + s];
    __syncthreads();
  }
  if (t == 0) {
    const float mean = s_par[0] * (1.f / 8192.f);
    const float var = sr[0] * (1.f / 8192.f) - mean * mean;
    const float sc = g[o] * rsqrtf(var + BNEPS);
    s_par[0] = sc;
    s_par[1] = bb[o] - mean * sc;
  }
  __syncthreads();
  const float sc = s_par[0], sh = s_par[1];
  const int lane = t & 63, w = t >> 6;
#pragma unroll
  for (int h = 0; h < 2; ++h) {
    const int b = w + h * 4;
    const float* yr = Y5 + ((size_t)((b << 10) + o)) * 1024 + lane * 16;
    float mx = -3.4e38f, sm = 0.f;
#pragma unroll
    for (int j = 0; j < 4; ++j) {
      const float4 v = *(const float4*)&yr[j * 4];
      const float y0 = lrelu(fmaf(sc, v.x, sh));
      const float y1 = lrelu(fmaf(sc, v.y, sh));
      const float y2 = lrelu(fmaf(sc, v.z, sh));
      const float y3 = lrelu(fmaf(sc, v.w, sh));
      mx = fmaxf(fmaxf(fmaxf(mx, y0), fmaxf(y1, y2)), y3);
      sm += y0 + y1 + y2 + y3;
    }
#pragma unroll
    for (int off = 1; off < 64; off <<= 1) {
      mx = fmaxf(mx, __shfl_xor(mx, off, 64));
      sm += __shfl_xor(sm, off, 64);
    }
    if (lane == 0) {
      z[b * 2048 + o] = mx;
      z[b * 2048 + 1024 + o] = sm * (1.f / 1024.f);
    }
  }
}

// ---------------------------------------------------------------------------
// fallback f32 conv1d (used only if ws too small for MFMA buffers)
// ---------------------------------------------------------------------------
__global__ void bn_finalize_kernel(float* __restrict__ stats,
                                   const float* __restrict__ g,
                                   const float* __restrict__ bb, int cout,
                                   float inv_cnt) {
  const int o = blockIdx.x * 256 + threadIdx.x;
  if (o >= cout) return;
  const float mean = stats[o] * inv_cnt;
  const float var = stats[1024 + o] * inv_cnt - mean * mean;
  const float s = g[o] * rsqrtf(var + BNEPS);
  stats[2048 + o] = s;
  stats[3072 + o] = bb[o] - mean * s;
}

__global__ __launch_bounds__(256) void conv1d_gemm_kernel(
    const float* __restrict__ hcat, const float* __restrict__ WT5,
    float* __restrict__ stats, float* __restrict__ Y5) {
  __shared__ __align__(16) float s_w[8][64];
  __shared__ __align__(16) float s_h[8][64];
  __shared__ __align__(16) float s_red[64][16];
  const int t = threadIdx.x;
  const int bx = blockIdx.x;
  const int b = bx >> 8;
  const int o0 = ((bx >> 4) & 15) * 64;
  const int n0 = (bx & 15) * 64;
  const float* hb = hcat + (size_t)b * (512 * 1024);
  const int to = (t >> 4) * 4;
  const int tn = (t & 15) * 4;
  float acc[4][4] = {};
  for (int c0 = 0; c0 < 512; c0 += 8) {
    for (int i = t; i < 8 * 64; i += 256) {
      const int cc = i >> 6, col = i & 63;
      s_w[cc][col] = WT5[(c0 + cc) * 1024 + o0 + col];
      s_h[cc][col] = hb[(c0 + cc) * NN + n0 + col];
    }
    __syncthreads();
#pragma unroll
    for (int cc = 0; cc < 8; ++cc) {
      const float4 wv = *(const float4*)&s_w[cc][to];
      const float4 hv = *(const float4*)&s_h[cc][tn];
      const float wa[4] = {wv.x, wv.y, wv.z, wv.w};
      const float ha[4] = {hv.x, hv.y, hv.z, hv.w};
#pragma unroll
      for (int i = 0; i < 4; ++i)
#pragma unroll
        for (int j = 0; j < 4; ++j) acc[i][j] = fmaf(wa[i], ha[j], acc[i][j]);
    }
    __syncthreads();
  }
#pragma unroll
  for (int i = 0; i < 4; ++i) {
    *(float4*)&Y5[((size_t)(b << 10) + o0 + to + i) * NN + n0 + tn] =
        make_float4(acc[i][0], acc[i][1], acc[i][2], acc[i][3]);
  }
#pragma unroll
  for (int i = 0; i < 4; ++i)
    s_red[to + i][t & 15] = acc[i][0] + acc[i][1] + acc[i][2] + acc[i][3];
  __syncthreads();
  if (t < 64) {
    float s = 0.f;
#pragma unroll
    for (int g2 = 0; g2 < 16; ++g2) s += s_red[t][g2];
    atomicAdd(&stats[o0 + t], s);
  }
  __syncthreads();
#pragma unroll
  for (int i = 0; i < 4; ++i) {
    float s = 0.f;
#pragma unroll
    for (int j = 0; j < 4; ++j) s = fmaf(acc[i][j], acc[i][j], s);
    s_red[to + i][t & 15] = s;
  }
  __syncthreads();
  if (t < 64) {
    float s = 0.f;
#pragma unroll
    for (int g2 = 0; g2 < 16; ++g2) s += s_red[t][g2];
    atomicAdd(&stats[1024 + o0 + t], s);
  }
}

__global__ __launch_bounds__(256) void pool_kernel(
    const float* __restrict__ Y5, const float* __restrict__ stats,
    float* __restrict__ z) {
  const int t = threadIdx.x;
  const int lane = t & 63;
  const int bx = blockIdx.x;
  const int b = bx >> 8;
  const int o = (bx & 255) * 4 + (t >> 6);
  const float sc = stats[2048 + o], sh = stats[3072 + o];
  const float* yr = Y5 + ((size_t)(b << 10) + o) * NN;
  float mx = -3.4e38f, sm = 0.f;
#pragma unroll
  for (int j = 0; j < 16; ++j) {
    const float y = lrelu(fmaf(sc, yr[j * 64 + lane], sh));
    mx = fmaxf(mx, y);
    sm += y;
  }
  for (int off = 32; off > 0; off >>= 1) {
    mx = fmaxf(mx, __shfl_down(mx, off, 64));
    sm += __shfl_down(sm, off, 64);
  }
  if (lane == 0) {
    z[b * 2048 + o] = mx;
    z[b * 2048 + 1024 + o] = sm * (1.f / 1024.f);
  }
}

// ---------------------------------------------------------------------------
// MLP layer with batch-of-8 BN + lrelu fused.
// ---------------------------------------------------------------------------
__global__ __launch_bounds__(256) void mlp_kernel(
    const float* __restrict__ zin, const float* __restrict__ W,
    const float* __restrict__ bias, const float* __restrict__ g,
    const float* __restrict__ bb, int kin, float* __restrict__ out, int O) {
  __shared__ float s_red[256];
  __shared__ float s_y[8];
  const int t = threadIdx.x;
  const int o = blockIdx.x;
  float acc[8];
#pragma unroll
  for (int b = 0; b < 8; ++b) acc[b] = 0.f;
  for (int c = t; c < kin; c += 256) {
    const float w = W[(size_t)o * kin + c];
#pragma unroll
    for (int b = 0; b < 8; ++b) acc[b] = fmaf(w, zin[b * kin + c], acc[b]);
  }
  for (int b = 0; b < 8; ++b) {
    s_red[t] = acc[b];
    __syncthreads();
    for (int s = 128; s > 0; s >>= 1) {
      if (t < s) s_red[t] += s_red[t + s];
      __syncthreads();
    }
    if (t == 0) s_y[b] = s_red[0] + (bias ? bias[o] : 0.f);
    __syncthreads();
  }
  if (t == 0) {
    float m = 0.f;
    for (int b = 0; b < 8; ++b) m += s_y[b];
    m *= 0.125f;
    float v = 0.f;
    for (int b = 0; b < 8; ++b) { const float d = s_y[b] - m; v = fmaf(d, d, v); }
    v *= 0.125f;
    const float s = g[o] * rsqrtf(v + BNEPS);
    const float sh = bb[o] - m * s;
    for (int b = 0; b < 8; ++b) out[b * O + o] = lrelu(fmaf(s, s_y[b], sh));
  }
}

// final: out = z2 @ Wl3^T + bl3; output dtype derived from flags here.
__global__ void final_kernel(const float* __restrict__ z2,
                             const float* __restrict__ Wl3,
                             const float* __restrict__ bl3,
                             const int* __restrict__ flags, void* out) {
  const int j = blockIdx.x * 256 + threadIdx.x;
  if (j >= 320) return;
  int anyf32 = 0, anybf = 0;
  for (int i = 0; i < NIN; ++i) {
    const int fl = flags[i];
    if (fl == 0) anyf32 = 1;
    if (fl == 1) anybf = 1;
  }
  const int bf16out = (anybf && !anyf32) ? 1 : 0;
  const int b = j / 40, o = j - b * 40;
  float s = bl3[o];
  for (int c = 0; c < 256; ++c) s = fmaf(z2[b * 256 + c], Wl3[o * 256 + c], s);
  if (bf16out) ((__hip_bfloat16*)out)[j] = __float2bfloat16(s);
  else ((float*)out)[j] = s;
}

// ---------------------------------------------------------------------------
template <int C, int O>
static void run_stage(float* wsf, const float* xbase, int bstr, int widx,
                      int gidx, int bidx, int stat, float* hout,
                      unsigned short* hp, int coff, hipStream_t stream) {
  int* idxb = reinterpret_cast<int*>(wsf + IDXo);
  float* dist = wsf + DISTo;
  float* U = wsf + U_OFF;
  float* Vd = wsf + VD_OFF;
  float* ymx = wsf + YMX_OFF;
  float* ymn = wsf + YMN_OFF;
  float* stats = wsf + STATSo + stat * 4096;
  dist2_kernel<C><<<512, 256, 0, stream>>>(xbase, bstr, dist);
  tg_kernel<C, O><<<2048 + BB * 16 * (O / 64), 256, 0, stream>>>(
      dist, idxb, xbase, bstr, wsf + widx, U, Vd);
  edge_pass_kernel<O><<<512, 256, 0, stream>>>(U, Vd, idxb, stats, ymx, ymn);
  bn_apply_kernel<O><<<BB * 32 * (O / 32), 256, 0, stream>>>(
      ymx, ymn, stats, wsf + gidx, wsf + bidx, hout, hp, coff);
}

extern "C" void kernel_launch(void* const* d_in, const int* in_sizes, int n_in,
                              void* d_out, int out_size, void* d_ws,
                              size_t ws_size, hipStream_t stream) {
  (void)in_sizes; (void)n_in; (void)out_size;
  float* wsf = reinterpret_cast<float*>(d_ws);
  int* flags = reinterpret_cast<int*>(wsf + FLAGSo);
  float* hcat = wsf + HCATo;
  const bool mf = ws_size >= WS_NEED_MFMA;
  unsigned short* hp = mf ? reinterpret_cast<unsigned short*>(wsf + HBFo) : nullptr;
  unsigned short* w5p = reinterpret_cast<unsigned short*>(wsf + W5BFo);

  Ptrs ptrs;
  for (int i = 0; i < NIN; ++i) ptrs.p[i] = d_in[i];

  detect_kernel<<<NIN, 64, 0, stream>>>(ptrs, flags);
  convert_kernel<<<NCONV + 80 + 256, 256, 0, stream>>>(ptrs, flags, wsf,
                                                       mf ? 1 : 0);

  run_stage<3, 64>(wsf, wsf + XIN, 3 * NN, WT1, G1, B1o, 0, hcat, hp, 0,
                   stream);
  run_stage<64, 64>(wsf, hcat, 512 * NN, WT2, G2, B2o, 1, hcat + 64 * NN, hp,
                    64, stream);
  run_stage<64, 128>(wsf, hcat + 64 * NN, 512 * NN, WT3, G3, B3o, 2,
                     hcat + 128 * NN, hp, 128, stream);
  run_stage<128, 256>(wsf, hcat + 128 * NN, 512 * NN, WT4, G4, B4o, 3,
                      hcat + 256 * NN, hp, 256, stream);

  // conv1d 512->1024 + BN + pool
  float* Y5 = wsf + Y5_OFF;
  float* st5 = wsf + STATSo + 4 * 4096;
  if (mf) {
    conv1d_mfma_kernel<<<512, 256, 0, stream>>>(hp, w5p, Y5);
    c1pool_kernel<<<1024, 256, 0, stream>>>(Y5, wsf + G5, wsf + B5o,
                                            wsf + Z2048o);
  } else {
    conv1d_gemm_kernel<<<2048, 256, 0, stream>>>(hcat, wsf + WT5, st5, Y5);
    bn_finalize_kernel<<<4, 256, 0, stream>>>(st5, wsf + G5, wsf + B5o, 1024,
                                              1.f / 8192.f);
    pool_kernel<<<BB * 256, 256, 0, stream>>>(Y5, st5, wsf + Z2048o);
  }

  // MLP head
  mlp_kernel<<<512, 256, 0, stream>>>(wsf + Z2048o, wsf + WL1, nullptr,
      wsf + G6, wsf + B6o, 2048, wsf + Z1o, 512);
  mlp_kernel<<<256, 256, 0, stream>>>(wsf + Z1o, wsf + WL2, wsf + BL2o,
      wsf + G7, wsf + B7o, 512, wsf + Z2o, 256);
  final_kernel<<<2, 256, 0, stream>>>(wsf + Z2o, wsf + WL3, wsf + BL3o,
      flags, d_out);
}